// Round 5
// baseline (264.495 us; speedup 1.0000x reference)
//
#include <hip/hip_runtime.h>

// ---------- problem constants ----------
#define BATCH   2
#define SEQ     2048
#define DMODEL  1024
#define NHEAD   16
#define DKH     64
#define MTOT    (BATCH*SEQ)      // 4096 rows for the projection GEMMs
#define KDIM    DMODEL           // 1024 contraction for projections

// ws layout in bf16 elements (total 24M bf16 = 48 MB)
#define XB    0u                     // x bf16            [4096,1024]  4M
#define WQB   (4u*1024u*1024u)       // Wq bf16           [1024,1024]  1M
#define WKB   (5u*1024u*1024u)
#define WVB   (6u*1024u*1024u)
#define WOB   (7u*1024u*1024u)
#define QOFF  (8u*1024u*1024u)       // Q  [B,H,N,dk] (pre-scaled log2e/8) 4M
#define KOFF  (12u*1024u*1024u)      // K  [B,H,N,dk]                  4M
#define VOFF  (16u*1024u*1024u)      // V^T [B,H,dk,N]                 4M
#define OOFF  (20u*1024u*1024u)      // attn out, flat [B,N,D]         4M

typedef __bf16 bf16x8 __attribute__((ext_vector_type(8)));
typedef __bf16 bf16x4 __attribute__((ext_vector_type(4)));
typedef float  f32x4  __attribute__((ext_vector_type(4)));
typedef float  f32x16 __attribute__((ext_vector_type(16)));

// async global->LDS, 16B per lane; LDS dest is wave-uniform base (HW adds lane*16)
__device__ __forceinline__ void async16(const __bf16* g, __bf16* l) {
  __builtin_amdgcn_global_load_lds(
      (const __attribute__((address_space(1))) void*)g,
      (__attribute__((address_space(3))) void*)l, 16, 0, 0);
}

// packed f32x2 -> bf16x2 (dword): lo in low 16 bits (T12 recipe, no builtin)
__device__ __forceinline__ unsigned cvtpk_bf16(float lo, float hi) {
  unsigned r;
  asm("v_cvt_pk_bf16_f32 %0, %1, %2" : "=v"(r) : "v"(lo), "v"(hi));
  return r;
}
// v_permlane32_swap_b32: a.hi32lanes <-> b.lo32lanes
__device__ __forceinline__ void plswap(unsigned& a, unsigned& b) {
  asm("v_permlane32_swap_b32 %0, %1" : "+v"(a), "+v"(b));
}

// ---------------------------------------------------------------------------
// fp32 -> bf16 conversion: blockIdx.y selects tensor (0:x, 1..4:Wq/Wk/Wv/Wo)
// ---------------------------------------------------------------------------
__global__ __launch_bounds__(256) void cvt_fp32_bf16(
    const float* __restrict__ x,  const float* __restrict__ wq,
    const float* __restrict__ wk, const float* __restrict__ wv,
    const float* __restrict__ wo, __bf16* __restrict__ ws)
{
  const float* src; __bf16* dst; int n;
  switch (blockIdx.y) {
    case 0:  src = x;  dst = ws + XB;  n = 4 * 1024 * 1024; break;
    case 1:  src = wq; dst = ws + WQB; n = 1024 * 1024;     break;
    case 2:  src = wk; dst = ws + WKB; n = 1024 * 1024;     break;
    case 3:  src = wv; dst = ws + WVB; n = 1024 * 1024;     break;
    default: src = wo; dst = ws + WOB; n = 1024 * 1024;     break;
  }
  const int i = (blockIdx.x * 256 + threadIdx.x) * 8;
  if (i < n) {
    const float4 a = *(const float4*)(src + i);
    const float4 b = *(const float4*)(src + i + 4);
    bf16x8 o;
    o[0] = (__bf16)a.x; o[1] = (__bf16)a.y; o[2] = (__bf16)a.z; o[3] = (__bf16)a.w;
    o[4] = (__bf16)b.x; o[5] = (__bf16)b.y; o[6] = (__bf16)b.z; o[7] = (__bf16)b.w;
    *(bf16x8*)(dst + i) = o;
  }
}

// ---------------------------------------------------------------------------
// 128x128 NT-GEMM core, BK=32 (single-buffer — R2 showed explicit dbuf is
// net-negative here). lds: A-tile [0,4096), B-tile [4096,8192) (16 KB).
// 16B-chunk XOR swizzle: chunk' = chunk ^ (row & 3).
// ---------------------------------------------------------------------------
__device__ __forceinline__ void gemm128_core(
    const __bf16* __restrict__ A, const __bf16* __restrict__ W,
    int m0, int n0, __bf16* lds, f32x4 (&acc)[4][4])
{
  __bf16* A_lds = lds;
  __bf16* B_lds = lds + 4096;
  const int t    = threadIdx.x;
  const int w    = t >> 6;
  const int lane = t & 63;
  const int ln15 = lane & 15;
  const int quad = lane >> 4;
  const int wr   = (w >> 1) << 6;   // wave row offset within 128
  const int wc   = (w & 1) << 6;    // wave col offset within 128

#pragma unroll
  for (int i = 0; i < 4; ++i)
#pragma unroll
    for (int j = 0; j < 4; ++j) acc[i][j] = (f32x4){0.f, 0.f, 0.f, 0.f};

  for (int kt = 0; kt < KDIM; kt += 32) {
    __syncthreads();   // previous tile's LDS reads done
#pragma unroll
    for (int issue = 0; issue < 2; ++issue) {
      const int cbase = issue * 256 + (w << 6);
      const int c     = cbase + lane;
      const int row   = c >> 2;                       // 4 chunks (32 bf16) per row
      const int goff  = ((c & 3) ^ (row & 3)) << 3;   // swizzled source chunk
      async16(A + (size_t)(m0 + row) * KDIM + kt + goff, A_lds + cbase * 8);
      async16(W + (size_t)(n0 + row) * KDIM + kt + goff, B_lds + cbase * 8);
    }
    __syncthreads();   // vmcnt(0) drain: LDS tiles valid

    bf16x8 af[4], bfr[4];
#pragma unroll
    for (int i = 0; i < 4; ++i) {
      const int row = wr + i * 16 + ln15;
      af[i] = *(const bf16x8*)&A_lds[row * 32 + ((quad ^ (row & 3)) << 3)];
    }
#pragma unroll
    for (int j = 0; j < 4; ++j) {
      const int row = wc + j * 16 + ln15;
      bfr[j] = *(const bf16x8*)&B_lds[row * 32 + ((quad ^ (row & 3)) << 3)];
    }
#pragma unroll
    for (int i = 0; i < 4; ++i)
#pragma unroll
      for (int j = 0; j < 4; ++j)
        acc[i][j] = __builtin_amdgcn_mfma_f32_16x16x32_bf16(af[i], bfr[j], acc[i][j], 0, 0, 0);
  }
}

// ---------------------------------------------------------------------------
// Fused QKV projection: z=0 -> Q (scaled log2e/8) [B,H,N,dk]; z=1 -> K;
// z=2 -> V transposed [B,H,dk,N]. Biases fp32. 16B vectorized stores via
// per-wave LDS repack.
// ---------------------------------------------------------------------------
__global__ __launch_bounds__(256) void qkv_gemm(
    const __bf16* __restrict__ X,
    const __bf16* __restrict__ Wq, const float* __restrict__ bq,
    const __bf16* __restrict__ Wk, const float* __restrict__ bk,
    const __bf16* __restrict__ Wv, const float* __restrict__ bv,
    __bf16* __restrict__ ws)
{
  __shared__ __align__(16) __bf16 lds[128 * 64];   // 16 KB

  const int z = blockIdx.z;
  const __bf16* W    = (z == 0) ? Wq : (z == 1) ? Wk : Wv;
  const float*  bias = (z == 0) ? bq : (z == 1) ? bk : bv;
  __bf16* out = ws + ((z == 0) ? QOFF : (z == 1) ? KOFF : VOFF);
  // softmax runs in exp2 domain: fold 1/sqrt(dk) * log2(e) into Q
  const float scale = (z == 0) ? 0.125f * 1.44269504088896f : 1.0f;

  const int m0 = blockIdx.x * 128;
  const int n0 = blockIdx.y * 128;

  f32x4 acc[4][4];
  gemm128_core(X, W, m0, n0, lds, acc);

  const int t = threadIdx.x, w = t >> 6, lane = t & 63;
  const int ln15 = lane & 15, quad = lane >> 4;
  const int wr = (w >> 1) << 6, wc = (w & 1) << 6;

  // bias values for this wave's 64 columns (col = j*16+ln15)
  float bj4[4];
#pragma unroll
  for (int j = 0; j < 4; ++j) bj4[j] = bias[n0 + wc + j * 16 + ln15];

  __syncthreads();                     // all waves done reading K-tiles
  __bf16* scr = lds + (w << 10);       // per-wave 1024-elem scratch (2 KB)

  const int bb = m0 >> 11;             // batch (blocks never straddle)
  const int s_base = (m0 & 2047) + wr;
  const int h = (n0 + wc) >> 6;

  if (z != 2) {
    // ---- Q/K [B,H,N,dk]: row-major scratch [row16][d64], coalesced stores
    const int rdrow = lane & 15, rdseg = lane >> 4;
#pragma unroll
    for (int i = 0; i < 4; ++i) {
#pragma unroll
      for (int j = 0; j < 4; ++j)
#pragma unroll
        for (int rr = 0; rr < 4; ++rr)
          scr[(quad * 4 + rr) * 64 + j * 16 + ln15] =
              (__bf16)((acc[i][j][rr] + bj4[j]) * scale);
      // wave-private scratch: compiler orders via lgkmcnt, no barrier
      bf16x8 v0 = *(const bf16x8*)&scr[rdrow * 64 + rdseg * 16];
      bf16x8 v1 = *(const bf16x8*)&scr[rdrow * 64 + rdseg * 16 + 8];
      const int s = s_base + i * 16 + rdrow;
      __bf16* p = out + (((size_t)(bb * NHEAD + h)) * SEQ + s) * DKH + rdseg * 16;
      *(bf16x8*)p = v0;
      *(bf16x8*)&p[8] = v1;
    }
  } else {
    // ---- V^T [B,H,dk,N]: col-major scratch [d64][row16] does the transpose;
    // each lane then stores 32B contiguous in s.
#pragma unroll
    for (int i = 0; i < 4; ++i) {
#pragma unroll
      for (int j = 0; j < 4; ++j) {
        bf16x4 pk;
#pragma unroll
        for (int rr = 0; rr < 4; ++rr) pk[rr] = (__bf16)(acc[i][j][rr] + bj4[j]);
        *(bf16x4*)&scr[(j * 16 + ln15) * 16 + quad * 4] = pk;
      }
      bf16x8 c0 = *(const bf16x8*)&scr[lane * 16];
      bf16x8 c1 = *(const bf16x8*)&scr[lane * 16 + 8];
      __bf16* p = out + (((size_t)(bb * NHEAD + h)) * DKH + lane) * SEQ
                      + s_base + i * 16;
      *(bf16x8*)p = c0;
      *(bf16x8*)&p[8] = c1;
    }
  }
}

// ---------------------------------------------------------------------------
// Output projection: d_out(fp32) = O[M,K]bf16 @ Wo[N,K]bf16^T + bo(fp32).
// 64x128 tile -> 512 blocks (2/CU). 4 waves, each 64 rows x 32 cols.
// ---------------------------------------------------------------------------
__global__ __launch_bounds__(256) void out_gemm(
    const __bf16* __restrict__ A, const __bf16* __restrict__ Wo,
    const float* __restrict__ bo, float* __restrict__ out)
{
  __shared__ __align__(16) __bf16 lds[6144];   // A 64x32 | B 128x32 (12 KB)
  __bf16* A_lds = lds;
  __bf16* B_lds = lds + 2048;

  const int m0 = blockIdx.x * 64;
  const int n0 = blockIdx.y * 128;

  const int t = threadIdx.x, w = t >> 6, lane = t & 63;
  const int ln15 = lane & 15, quad = lane >> 4;

  f32x4 acc[4][2];
#pragma unroll
  for (int i = 0; i < 4; ++i)
#pragma unroll
    for (int j = 0; j < 2; ++j) acc[i][j] = (f32x4){0.f, 0.f, 0.f, 0.f};

  for (int kt = 0; kt < KDIM; kt += 32) {
    __syncthreads();
    {  // A: 64 rows x 4 chunks = 256 chunks = 1 issue
      const int c = (w << 6) + lane;
      const int row = c >> 2;
      const int goff = ((c & 3) ^ (row & 3)) << 3;
      async16(A + (size_t)(m0 + row) * KDIM + kt + goff, A_lds + c * 8);
    }
#pragma unroll
    for (int issue = 0; issue < 2; ++issue) {  // B: 128 rows x 4 chunks = 2 issues
      const int cbase = issue * 256 + (w << 6);
      const int c = cbase + lane;
      const int row = c >> 2;
      const int goff = ((c & 3) ^ (row & 3)) << 3;
      async16(Wo + (size_t)(n0 + row) * KDIM + kt + goff, B_lds + cbase * 8);
    }
    __syncthreads();

    bf16x8 af[4], bfr[2];
#pragma unroll
    for (int i = 0; i < 4; ++i) {
      const int row = i * 16 + ln15;
      af[i] = *(const bf16x8*)&A_lds[row * 32 + ((quad ^ (row & 3)) << 3)];
    }
#pragma unroll
    for (int j = 0; j < 2; ++j) {
      const int row = (w << 5) + j * 16 + ln15;
      bfr[j] = *(const bf16x8*)&B_lds[row * 32 + ((quad ^ (row & 3)) << 3)];
    }
#pragma unroll
    for (int i = 0; i < 4; ++i)
#pragma unroll
      for (int j = 0; j < 2; ++j)
        acc[i][j] = __builtin_amdgcn_mfma_f32_16x16x32_bf16(af[i], bfr[j], acc[i][j], 0, 0, 0);
  }

  float bj2[2];
#pragma unroll
  for (int j = 0; j < 2; ++j) bj2[j] = bo[n0 + (w << 5) + j * 16 + ln15];

  __syncthreads();                          // waves done reading A/B tiles
  float* scrf = (float*)lds + (w << 9);     // per-wave 512-float scratch (2 KB)

  const int rdrow = lane & 15, rdseg = lane >> 4;
#pragma unroll
  for (int i = 0; i < 4; ++i) {
#pragma unroll
    for (int j = 0; j < 2; ++j) {
      f32x4 v;
#pragma unroll
      for (int rr = 0; rr < 4; ++rr) v[rr] = acc[i][j][rr] + bj2[j];
      *(f32x4*)&scrf[(j * 16 + ln15) * 16 + quad * 4] = v;   // col-major
    }
    const int m = m0 + i * 16 + rdrow;
    float* p = out + (size_t)m * DMODEL + n0 + (w << 5) + rdseg * 8;
#pragma unroll
    for (int cc = 0; cc < 2; ++cc) {
      f32x4 v;
#pragma unroll
      for (int e = 0; e < 4; ++e)
        v[e] = scrf[(rdseg * 8 + cc * 4 + e) * 16 + rdrow];
      *(f32x4*)&p[cc * 4] = v;
    }
  }
}

// ---------------------------------------------------------------------------
// softmax fragment build (T12): s holds S^T regs for one 32-key block
// (key = (r&3) + 8*(r>>2) + 4*hl, q = ln31). exp2 in place, then
// cvt_pk pairs + permlane32_swap reassemble the PV A-fragments entirely
// in registers — no P LDS round-trip.
// ---------------------------------------------------------------------------
__device__ __forceinline__ void softmax_frag(const f32x16& s, float& l,
                                             bf16x8& pfa, bf16x8& pfb)
{
  float p[16];
#pragma unroll
  for (int r = 0; r < 16; ++r) {
    p[r] = __builtin_amdgcn_exp2f(s[r]);
    l += p[r];
  }
  unsigned A0 = cvtpk_bf16(p[0],  p[1]);   // (0,1)   | (4,5)
  unsigned A1 = cvtpk_bf16(p[2],  p[3]);   // (2,3)   | (6,7)
  unsigned B0 = cvtpk_bf16(p[4],  p[5]);   // (8,9)   | (12,13)
  unsigned B1 = cvtpk_bf16(p[6],  p[7]);   // (10,11) | (14,15)
  unsigned C0 = cvtpk_bf16(p[8],  p[9]);   // (16,17) | (20,21)
  unsigned C1 = cvtpk_bf16(p[10], p[11]);  // (18,19) | (22,23)
  unsigned D0 = cvtpk_bf16(p[12], p[13]);  // (24,25) | (28,29)
  unsigned D1 = cvtpk_bf16(p[14], p[15]);  // (26,27) | (30,31)
  plswap(A0, B0);
  plswap(A1, B1);
  plswap(C0, D0);
  plswap(C1, D1);
  union { unsigned u[4]; bf16x8 v; } ua, ub;
  ua.u[0] = A0; ua.u[1] = A1; ua.u[2] = B0; ua.u[3] = B1;  // k 0..7 | 8..15
  ub.u[0] = C0; ub.u[1] = C1; ub.u[2] = D0; ub.u[3] = D1;  // k 16..23 | 24..31
  pfa = ua.v;
  pfb = ub.v;
}

// ---------------------------------------------------------------------------
// PV step (key-quarter form): A-frag PF covers keys kq*32 + KS*16 + hl*8..+8
// ---------------------------------------------------------------------------
__device__ __forceinline__ void pvstep(const __bf16* Vs, int kq, int KS, int hl,
                                       int ln31, const bf16x8& PF,
                                       f32x16& o0, f32x16& o1)
{
  const int vchunk = (kq << 2) + 2 * KS + hl;
  bf16x8 vf0 = *(const bf16x8*)&Vs[ln31 * 128 + ((vchunk ^ (ln31 & 15)) << 3)];
  bf16x8 vf1 = *(const bf16x8*)&Vs[(32 + ln31) * 128 +
                                   ((vchunk ^ ((32 + ln31) & 15)) << 3)];
  o0 = __builtin_amdgcn_mfma_f32_32x32x16_bf16(PF, vf0, o0, 0, 0, 0);
  o1 = __builtin_amdgcn_mfma_f32_32x32x16_bf16(PF, vf1, o1, 0, 0, 0);
}

// ---------------------------------------------------------------------------
// Flash attention v11 — KEY-SPLIT x4, 16-WAVE BLOCKS, 32 WAVES/CU (hw max).
// R1's key-split (8->16 waves/CU) was the biggest verified win (53->44.4);
// this pushes the same lever to the occupancy cap. 1024 threads = 4 q-groups
// x 4 key-quarters; per-wave inner loop is a strict SUBSET of the verified
// R1 path (one 32-key block per staged tile). Same staging, same barriers,
// same LDS (48 KB -> 2 blocks/CU), same op counts — only concurrency x2.
// VGPR must stay <= 64 for 8 waves/SIMD: launch_bounds(1024, 8) pins it
// (R1 inner measured 60 under a looser bound).
// Final combine: 3-round LDS tree (kq 1,2,3 -> kq 0) through dead Q/K LDS.
// ---------------------------------------------------------------------------
__global__ __launch_bounds__(1024, 8) void attn_kernel(
    const __bf16* __restrict__ Qb, const __bf16* __restrict__ Kb,
    const __bf16* __restrict__ Vtb, __bf16* __restrict__ Ob)
{
  __shared__ __align__(16) __bf16 smem[3 * 128 * 64];   // 48 KB
  __bf16* QP = smem;            // Q tile [q128][dk64]
  __bf16* Ks = smem + 8192;     // K tile [key128][dk64]
  __bf16* Vs = smem + 16384;    // V tile [d64][key128]

  const int t = threadIdx.x, w = t >> 6, lane = t & 63;
  const int ln31 = lane & 31, hl = lane >> 5;
  const int qg = w & 3;         // q-group (32 rows of the 128-q tile)
  const int kq = w >> 2;        // key-quarter (32 keys) of the staged tile
  const int bh = blockIdx.x;    // b*NHEAD + h  (XCD-locality key)
  const int q0 = blockIdx.y * 128;
  const int bb = bh >> 4, hh = bh & 15;

  const __bf16* Qg = Qb + (size_t)bh * SEQ * DKH + (size_t)q0 * DKH;
  const __bf16* Kg = Kb + (size_t)bh * SEQ * DKH;
  const __bf16* Vg = Vtb + (size_t)bh * DKH * SEQ;

  // stage Q tile: 1024 chunks / 1024 threads = 1 issue
  {
    const int c = t;
    const int row = c >> 3;                         // 8 chunks per 64-elem row
    const int goff = ((c & 7) ^ (row & 7)) << 3;
    async16(Qg + (size_t)row * DKH + goff, QP + c * 8);
  }
  __syncthreads();

  // Q B-fragments for this wave's 32 q-rows (held in regs for whole kernel)
  const int qrow = (qg << 5) + ln31;
  bf16x8 qf[4];
#pragma unroll
  for (int ks = 0; ks < 4; ++ks) {
    const int chunk = ((2 * ks + hl) ^ (qrow & 7));
    qf[ks] = *(const bf16x8*)&QP[qrow * 64 + (chunk << 3)];
  }

  float l_lane = 0.f;          // partial row-sum for q-row `qrow` (this quarter)
  f32x16 o0, o1;               // partial O[32q][64d]: d-blocks 0/1; d = db*32+ln31
#pragma unroll
  for (int r = 0; r < 16; ++r) { o0[r] = 0.f; o1[r] = 0.f; }

  for (int kt = 0; kt < SEQ; kt += 128) {
    __syncthreads();   // prior tile's Ks/Vs reads done; iter 0: Q reads done
    {
      const int c = t;
      // K [128 keys][64 dk]: 8 chunks/row — 1024 chunks / 1024 threads
      const int krow = c >> 3;
      const int kgoff = ((c & 7) ^ (krow & 7)) << 3;
      async16(Kg + (size_t)(kt + krow) * DKH + kgoff, Ks + c * 8);
      // V [64 d][128 keys]: 16 chunks/row — 1024 chunks / 1024 threads
      const int vrow = c >> 4;
      const int vgoff = ((c & 15) ^ (vrow & 15)) << 3;
      async16(Vg + (size_t)vrow * SEQ + kt + vgoff, Vs + c * 8);
    }
    __syncthreads();   // staging drain: Ks/Vs valid

    // ---- this wave's single 32-key block of the staged 128 ----
    f32x16 s;
#pragma unroll
    for (int r = 0; r < 16; ++r) s[r] = 0.f;
    const int kr = (kq << 5) + ln31;
    __builtin_amdgcn_s_setprio(1);
#pragma unroll
    for (int ks = 0; ks < 4; ++ks) {
      bf16x8 kf = *(const bf16x8*)&Ks[kr * 64 + (((2 * ks + hl) ^ (kr & 7)) << 3)];
      s = __builtin_amdgcn_mfma_f32_32x32x16_bf16(kf, qf[ks], s, 0, 0, 0);
    }
    __builtin_amdgcn_s_setprio(0);
    bf16x8 pa, pb;
    softmax_frag(s, l_lane, pa, pb);
    __builtin_amdgcn_s_setprio(1);
    pvstep(Vs, kq, 0, hl, ln31, pa, o0, o1);
    pvstep(Vs, kq, 1, hl, ln31, pb, o0, o1);
    __builtin_amdgcn_s_setprio(0);
  }

  // ---- cross-wave combine: 4 waves (kq 0..3) share each q-group.
  // 3 rounds: waves kq==r dump partial O (8 KB per qg) + l into dead LDS;
  // kq==0 accumulates. Round regions: 4 qg x 8 KB = 32 KB (QP+Ks, dead).
  __syncthreads();                       // all Ks/Vs LDS reads done
  float* cmb = (float*)smem;             // per-qg region: [d64][q32] f32
  const int dsw = ln31 & 7;
  l_lane += __shfl_xor(l_lane, 32);      // merge hl halves (same q-row)

#pragma unroll
  for (int r = 1; r < 4; ++r) {
    if (kq == r) {
      float* base = cmb + (qg << 11);
#pragma unroll
      for (int gg = 0; gg < 4; ++gg) {
        const int qq = ((2 * gg + hl) ^ dsw) << 2;   // swizzled q-quad slot
        f32x4 va, vb;
#pragma unroll
        for (int rr = 0; rr < 4; ++rr) { va[rr] = o0[4 * gg + rr]; vb[rr] = o1[4 * gg + rr]; }
        *(f32x4*)&base[ln31 * 32 + qq]        = va;   // d = ln31
        *(f32x4*)&base[(32 + ln31) * 32 + qq] = vb;   // d = 32+ln31
      }
      if (hl == 0) cmb[8192 + (qg << 5) + ln31] = l_lane;   // l region (Vs)
    }
    __syncthreads();
    if (kq == 0) {
      float* base = cmb + (qg << 11);
#pragma unroll
      for (int gg = 0; gg < 4; ++gg) {
        const int qq = ((2 * gg + hl) ^ dsw) << 2;
        const f32x4 va = *(const f32x4*)&base[ln31 * 32 + qq];
        const f32x4 vb = *(const f32x4*)&base[(32 + ln31) * 32 + qq];
#pragma unroll
        for (int rr = 0; rr < 4; ++rr) { o0[4 * gg + rr] += va[rr]; o1[4 * gg + rr] += vb[rr]; }
      }
      l_lane += cmb[8192 + (qg << 5) + ln31];
    }
    __syncthreads();
  }

  if (kq == 0) {
    const float inv = 1.0f / l_lane;

    // epilogue: O[b, q, h*64+d]; lane = d col; fetch inv via shfl
#pragma unroll
    for (int r = 0; r < 16; ++r) {
      const int qi = (r & 3) + 8 * (r >> 2) + 4 * hl;    // q within wave's 32
      const float iq = __shfl(inv, qi);                  // from lane qi (hl=0 half)
      const int q = q0 + (qg << 5) + qi;
      __bf16* rowp = Ob + ((size_t)(bb * SEQ + q)) * DMODEL + hh * DKH;
      rowp[ln31]      = (__bf16)(o0[r] * iq);
      rowp[32 + ln31] = (__bf16)(o1[r] * iq);
    }
  }
}

// ---------------------------------------------------------------------------
extern "C" void kernel_launch(void* const* d_in, const int* in_sizes, int n_in,
                              void* d_out, int out_size, void* d_ws, size_t ws_size,
                              hipStream_t stream)
{
  const float* x  = (const float*)d_in[0];
  const float* Wq = (const float*)d_in[1];
  const float* bq = (const float*)d_in[2];
  const float* Wk = (const float*)d_in[3];
  const float* bk = (const float*)d_in[4];
  const float* Wv = (const float*)d_in[5];
  const float* bv = (const float*)d_in[6];
  const float* Wo = (const float*)d_in[7];
  const float* bo = (const float*)d_in[8];
  float*  out = (float*)d_out;
  __bf16* ws  = (__bf16*)d_ws;

  // fp32 -> bf16 for x and the 4 weight matrices (one launch)
  cvt_fp32_bf16<<<dim3(2048, 5, 1), 256, 0, stream>>>(x, Wq, Wk, Wv, Wo, ws);

  // Q,K,V projections (fused, grid.z picks the matrix)
  qkv_gemm<<<dim3(MTOT / 128, DMODEL / 128, 3), 256, 0, stream>>>(
      ws + XB, ws + WQB, bq, ws + WKB, bk, ws + WVB, bv, ws);

  // flash attention: (bh, q-tile of 128) = 512 blocks x 1024 threads
  attn_kernel<<<dim3(BATCH * NHEAD, SEQ / 128), 1024, 0, stream>>>(
      ws + QOFF, ws + KOFF, ws + VOFF, ws + OOFF);

  // output projection -> fp32 d_out (64x128 tiles, 512 blocks)
  out_gemm<<<dim3(MTOT / 64, DMODEL / 128), 256, 0, stream>>>(
      ws + OOFF, ws + WOB, bo, out);
}

// Round 6
// 195.552 us; speedup vs baseline: 1.3526x; 1.3526x over previous
//
#include <hip/hip_runtime.h>

// ---------- problem constants ----------
#define BATCH   2
#define SEQ     2048
#define DMODEL  1024
#define NHEAD   16
#define DKH     64
#define MTOT    (BATCH*SEQ)      // 4096 rows for the projection GEMMs
#define KDIM    DMODEL           // 1024 contraction for projections

// ws layout in bf16 elements (total 24M bf16 = 48 MB)
#define XB    0u                     // x bf16            [4096,1024]  4M
#define WQB   (4u*1024u*1024u)       // Wq bf16           [1024,1024]  1M
#define WKB   (5u*1024u*1024u)
#define WVB   (6u*1024u*1024u)
#define WOB   (7u*1024u*1024u)
#define QOFF  (8u*1024u*1024u)       // Q  [B,H,N,dk] (pre-scaled log2e/8) 4M
#define KOFF  (12u*1024u*1024u)      // K  [B,H,N,dk]                  4M
#define VOFF  (16u*1024u*1024u)      // V^T [B,H,dk,N]                 4M
#define OOFF  (20u*1024u*1024u)      // attn out, flat [B,N,D]         4M

typedef __bf16 bf16x8 __attribute__((ext_vector_type(8)));
typedef __bf16 bf16x4 __attribute__((ext_vector_type(4)));
typedef float  f32x4  __attribute__((ext_vector_type(4)));
typedef float  f32x16 __attribute__((ext_vector_type(16)));

// async global->LDS, 16B per lane; LDS dest is wave-uniform base (HW adds lane*16)
__device__ __forceinline__ void async16(const __bf16* g, __bf16* l) {
  __builtin_amdgcn_global_load_lds(
      (const __attribute__((address_space(1))) void*)g,
      (__attribute__((address_space(3))) void*)l, 16, 0, 0);
}

// packed f32x2 -> bf16x2 (dword): lo in low 16 bits (T12 recipe, no builtin)
__device__ __forceinline__ unsigned cvtpk_bf16(float lo, float hi) {
  unsigned r;
  asm("v_cvt_pk_bf16_f32 %0, %1, %2" : "=v"(r) : "v"(lo), "v"(hi));
  return r;
}
// v_permlane32_swap_b32: a.hi32lanes <-> b.lo32lanes
__device__ __forceinline__ void plswap(unsigned& a, unsigned& b) {
  asm("v_permlane32_swap_b32 %0, %1" : "+v"(a), "+v"(b));
}

// ---------------------------------------------------------------------------
// fp32 -> bf16 conversion: blockIdx.y selects tensor (0:x, 1..4:Wq/Wk/Wv/Wo)
// ---------------------------------------------------------------------------
__global__ __launch_bounds__(256) void cvt_fp32_bf16(
    const float* __restrict__ x,  const float* __restrict__ wq,
    const float* __restrict__ wk, const float* __restrict__ wv,
    const float* __restrict__ wo, __bf16* __restrict__ ws)
{
  const float* src; __bf16* dst; int n;
  switch (blockIdx.y) {
    case 0:  src = x;  dst = ws + XB;  n = 4 * 1024 * 1024; break;
    case 1:  src = wq; dst = ws + WQB; n = 1024 * 1024;     break;
    case 2:  src = wk; dst = ws + WKB; n = 1024 * 1024;     break;
    case 3:  src = wv; dst = ws + WVB; n = 1024 * 1024;     break;
    default: src = wo; dst = ws + WOB; n = 1024 * 1024;     break;
  }
  const int i = (blockIdx.x * 256 + threadIdx.x) * 8;
  if (i < n) {
    const float4 a = *(const float4*)(src + i);
    const float4 b = *(const float4*)(src + i + 4);
    bf16x8 o;
    o[0] = (__bf16)a.x; o[1] = (__bf16)a.y; o[2] = (__bf16)a.z; o[3] = (__bf16)a.w;
    o[4] = (__bf16)b.x; o[5] = (__bf16)b.y; o[6] = (__bf16)b.z; o[7] = (__bf16)b.w;
    *(bf16x8*)(dst + i) = o;
  }
}

// ---------------------------------------------------------------------------
// 128x128 NT-GEMM core, BK=32 (single-buffer — R2 showed explicit dbuf is
// net-negative here). lds: A-tile [0,4096), B-tile [4096,8192) (16 KB).
// 16B-chunk XOR swizzle: chunk' = chunk ^ (row & 3).
// ---------------------------------------------------------------------------
__device__ __forceinline__ void gemm128_core(
    const __bf16* __restrict__ A, const __bf16* __restrict__ W,
    int m0, int n0, __bf16* lds, f32x4 (&acc)[4][4])
{
  __bf16* A_lds = lds;
  __bf16* B_lds = lds + 4096;
  const int t    = threadIdx.x;
  const int w    = t >> 6;
  const int lane = t & 63;
  const int ln15 = lane & 15;
  const int quad = lane >> 4;
  const int wr   = (w >> 1) << 6;   // wave row offset within 128
  const int wc   = (w & 1) << 6;    // wave col offset within 128

#pragma unroll
  for (int i = 0; i < 4; ++i)
#pragma unroll
    for (int j = 0; j < 4; ++j) acc[i][j] = (f32x4){0.f, 0.f, 0.f, 0.f};

  for (int kt = 0; kt < KDIM; kt += 32) {
    __syncthreads();   // previous tile's LDS reads done
#pragma unroll
    for (int issue = 0; issue < 2; ++issue) {
      const int cbase = issue * 256 + (w << 6);
      const int c     = cbase + lane;
      const int row   = c >> 2;                       // 4 chunks (32 bf16) per row
      const int goff  = ((c & 3) ^ (row & 3)) << 3;   // swizzled source chunk
      async16(A + (size_t)(m0 + row) * KDIM + kt + goff, A_lds + cbase * 8);
      async16(W + (size_t)(n0 + row) * KDIM + kt + goff, B_lds + cbase * 8);
    }
    __syncthreads();   // vmcnt(0) drain: LDS tiles valid

    bf16x8 af[4], bfr[4];
#pragma unroll
    for (int i = 0; i < 4; ++i) {
      const int row = wr + i * 16 + ln15;
      af[i] = *(const bf16x8*)&A_lds[row * 32 + ((quad ^ (row & 3)) << 3)];
    }
#pragma unroll
    for (int j = 0; j < 4; ++j) {
      const int row = wc + j * 16 + ln15;
      bfr[j] = *(const bf16x8*)&B_lds[row * 32 + ((quad ^ (row & 3)) << 3)];
    }
#pragma unroll
    for (int i = 0; i < 4; ++i)
#pragma unroll
      for (int j = 0; j < 4; ++j)
        acc[i][j] = __builtin_amdgcn_mfma_f32_16x16x32_bf16(af[i], bfr[j], acc[i][j], 0, 0, 0);
  }
}

// ---------------------------------------------------------------------------
// Fused QKV projection: z=0 -> Q (scaled log2e/8) [B,H,N,dk]; z=1 -> K;
// z=2 -> V transposed [B,H,dk,N]. Biases fp32. 16B vectorized stores via
// per-wave LDS repack.
// ---------------------------------------------------------------------------
__global__ __launch_bounds__(256) void qkv_gemm(
    const __bf16* __restrict__ X,
    const __bf16* __restrict__ Wq, const float* __restrict__ bq,
    const __bf16* __restrict__ Wk, const float* __restrict__ bk,
    const __bf16* __restrict__ Wv, const float* __restrict__ bv,
    __bf16* __restrict__ ws)
{
  __shared__ __align__(16) __bf16 lds[128 * 64];   // 16 KB

  const int z = blockIdx.z;
  const __bf16* W    = (z == 0) ? Wq : (z == 1) ? Wk : Wv;
  const float*  bias = (z == 0) ? bq : (z == 1) ? bk : bv;
  __bf16* out = ws + ((z == 0) ? QOFF : (z == 1) ? KOFF : VOFF);
  // softmax runs in exp2 domain: fold 1/sqrt(dk) * log2(e) into Q
  const float scale = (z == 0) ? 0.125f * 1.44269504088896f : 1.0f;

  const int m0 = blockIdx.x * 128;
  const int n0 = blockIdx.y * 128;

  f32x4 acc[4][4];
  gemm128_core(X, W, m0, n0, lds, acc);

  const int t = threadIdx.x, w = t >> 6, lane = t & 63;
  const int ln15 = lane & 15, quad = lane >> 4;
  const int wr = (w >> 1) << 6, wc = (w & 1) << 6;

  // bias values for this wave's 64 columns (col = j*16+ln15)
  float bj4[4];
#pragma unroll
  for (int j = 0; j < 4; ++j) bj4[j] = bias[n0 + wc + j * 16 + ln15];

  __syncthreads();                     // all waves done reading K-tiles
  __bf16* scr = lds + (w << 10);       // per-wave 1024-elem scratch (2 KB)

  const int bb = m0 >> 11;             // batch (blocks never straddle)
  const int s_base = (m0 & 2047) + wr;
  const int h = (n0 + wc) >> 6;

  if (z != 2) {
    // ---- Q/K [B,H,N,dk]: row-major scratch [row16][d64], coalesced stores
    const int rdrow = lane & 15, rdseg = lane >> 4;
#pragma unroll
    for (int i = 0; i < 4; ++i) {
#pragma unroll
      for (int j = 0; j < 4; ++j)
#pragma unroll
        for (int rr = 0; rr < 4; ++rr)
          scr[(quad * 4 + rr) * 64 + j * 16 + ln15] =
              (__bf16)((acc[i][j][rr] + bj4[j]) * scale);
      // wave-private scratch: compiler orders via lgkmcnt, no barrier
      bf16x8 v0 = *(const bf16x8*)&scr[rdrow * 64 + rdseg * 16];
      bf16x8 v1 = *(const bf16x8*)&scr[rdrow * 64 + rdseg * 16 + 8];
      const int s = s_base + i * 16 + rdrow;
      __bf16* p = out + (((size_t)(bb * NHEAD + h)) * SEQ + s) * DKH + rdseg * 16;
      *(bf16x8*)p = v0;
      *(bf16x8*)&p[8] = v1;
    }
  } else {
    // ---- V^T [B,H,dk,N]: col-major scratch [d64][row16] does the transpose;
    // each lane then stores 32B contiguous in s.
#pragma unroll
    for (int i = 0; i < 4; ++i) {
#pragma unroll
      for (int j = 0; j < 4; ++j) {
        bf16x4 pk;
#pragma unroll
        for (int rr = 0; rr < 4; ++rr) pk[rr] = (__bf16)(acc[i][j][rr] + bj4[j]);
        *(bf16x4*)&scr[(j * 16 + ln15) * 16 + quad * 4] = pk;
      }
      bf16x8 c0 = *(const bf16x8*)&scr[lane * 16];
      bf16x8 c1 = *(const bf16x8*)&scr[lane * 16 + 8];
      __bf16* p = out + (((size_t)(bb * NHEAD + h)) * DKH + lane) * SEQ
                      + s_base + i * 16;
      *(bf16x8*)p = c0;
      *(bf16x8*)&p[8] = c1;
    }
  }
}

// ---------------------------------------------------------------------------
// Output projection: d_out(fp32) = O[M,K]bf16 @ Wo[N,K]bf16^T + bo(fp32).
// 64x128 tile -> 512 blocks (2/CU). 4 waves, each 64 rows x 32 cols.
// ---------------------------------------------------------------------------
__global__ __launch_bounds__(256) void out_gemm(
    const __bf16* __restrict__ A, const __bf16* __restrict__ Wo,
    const float* __restrict__ bo, float* __restrict__ out)
{
  __shared__ __align__(16) __bf16 lds[6144];   // A 64x32 | B 128x32 (12 KB)
  __bf16* A_lds = lds;
  __bf16* B_lds = lds + 2048;

  const int m0 = blockIdx.x * 64;
  const int n0 = blockIdx.y * 128;

  const int t = threadIdx.x, w = t >> 6, lane = t & 63;
  const int ln15 = lane & 15, quad = lane >> 4;

  f32x4 acc[4][2];
#pragma unroll
  for (int i = 0; i < 4; ++i)
#pragma unroll
    for (int j = 0; j < 2; ++j) acc[i][j] = (f32x4){0.f, 0.f, 0.f, 0.f};

  for (int kt = 0; kt < KDIM; kt += 32) {
    __syncthreads();
    {  // A: 64 rows x 4 chunks = 256 chunks = 1 issue
      const int c = (w << 6) + lane;
      const int row = c >> 2;
      const int goff = ((c & 3) ^ (row & 3)) << 3;
      async16(A + (size_t)(m0 + row) * KDIM + kt + goff, A_lds + c * 8);
    }
#pragma unroll
    for (int issue = 0; issue < 2; ++issue) {  // B: 128 rows x 4 chunks = 2 issues
      const int cbase = issue * 256 + (w << 6);
      const int c = cbase + lane;
      const int row = c >> 2;
      const int goff = ((c & 3) ^ (row & 3)) << 3;
      async16(Wo + (size_t)(n0 + row) * KDIM + kt + goff, B_lds + cbase * 8);
    }
    __syncthreads();

    bf16x8 af[4], bfr[2];
#pragma unroll
    for (int i = 0; i < 4; ++i) {
      const int row = i * 16 + ln15;
      af[i] = *(const bf16x8*)&A_lds[row * 32 + ((quad ^ (row & 3)) << 3)];
    }
#pragma unroll
    for (int j = 0; j < 2; ++j) {
      const int row = (w << 5) + j * 16 + ln15;
      bfr[j] = *(const bf16x8*)&B_lds[row * 32 + ((quad ^ (row & 3)) << 3)];
    }
#pragma unroll
    for (int i = 0; i < 4; ++i)
#pragma unroll
      for (int j = 0; j < 2; ++j)
        acc[i][j] = __builtin_amdgcn_mfma_f32_16x16x32_bf16(af[i], bfr[j], acc[i][j], 0, 0, 0);
  }

  float bj2[2];
#pragma unroll
  for (int j = 0; j < 2; ++j) bj2[j] = bo[n0 + (w << 5) + j * 16 + ln15];

  __syncthreads();                          // waves done reading A/B tiles
  float* scrf = (float*)lds + (w << 9);     // per-wave 512-float scratch (2 KB)

  const int rdrow = lane & 15, rdseg = lane >> 4;
#pragma unroll
  for (int i = 0; i < 4; ++i) {
#pragma unroll
    for (int j = 0; j < 2; ++j) {
      f32x4 v;
#pragma unroll
      for (int rr = 0; rr < 4; ++rr) v[rr] = acc[i][j][rr] + bj2[j];
      *(f32x4*)&scrf[(j * 16 + ln15) * 16 + quad * 4] = v;   // col-major
    }
    const int m = m0 + i * 16 + rdrow;
    float* p = out + (size_t)m * DMODEL + n0 + (w << 5) + rdseg * 8;
#pragma unroll
    for (int cc = 0; cc < 2; ++cc) {
      f32x4 v;
#pragma unroll
      for (int e = 0; e < 4; ++e)
        v[e] = scrf[(rdseg * 8 + cc * 4 + e) * 16 + rdrow];
      *(f32x4*)&p[cc * 4] = v;
    }
  }
}

// ---------------------------------------------------------------------------
// softmax fragment build (T12): s holds S^T regs for one 32-key block
// (key = (r&3) + 8*(r>>2) + 4*hl, q = ln31). exp2 in place, then
// cvt_pk pairs + permlane32_swap reassemble the PV A-fragments entirely
// in registers — no P LDS round-trip.
// ---------------------------------------------------------------------------
__device__ __forceinline__ void softmax_frag(const f32x16& s, float& l,
                                             bf16x8& pfa, bf16x8& pfb)
{
  float p[16];
#pragma unroll
  for (int r = 0; r < 16; ++r) {
    p[r] = __builtin_amdgcn_exp2f(s[r]);
    l += p[r];
  }
  unsigned A0 = cvtpk_bf16(p[0],  p[1]);   // (0,1)   | (4,5)
  unsigned A1 = cvtpk_bf16(p[2],  p[3]);   // (2,3)   | (6,7)
  unsigned B0 = cvtpk_bf16(p[4],  p[5]);   // (8,9)   | (12,13)
  unsigned B1 = cvtpk_bf16(p[6],  p[7]);   // (10,11) | (14,15)
  unsigned C0 = cvtpk_bf16(p[8],  p[9]);   // (16,17) | (20,21)
  unsigned C1 = cvtpk_bf16(p[10], p[11]);  // (18,19) | (22,23)
  unsigned D0 = cvtpk_bf16(p[12], p[13]);  // (24,25) | (28,29)
  unsigned D1 = cvtpk_bf16(p[14], p[15]);  // (26,27) | (30,31)
  plswap(A0, B0);
  plswap(A1, B1);
  plswap(C0, D0);
  plswap(C1, D1);
  union { unsigned u[4]; bf16x8 v; } ua, ub;
  ua.u[0] = A0; ua.u[1] = A1; ua.u[2] = B0; ua.u[3] = B1;  // k 0..7 | 8..15
  ub.u[0] = C0; ub.u[1] = C1; ub.u[2] = D0; ub.u[3] = D1;  // k 16..23 | 24..31
  pfa = ua.v;
  pfb = ub.v;
}

// ---------------------------------------------------------------------------
// PV step (key-quarter form): A-frag PF covers keys kq*32 + KS*16 + hl*8..+8
// ---------------------------------------------------------------------------
__device__ __forceinline__ void pvstep(const __bf16* Vs, int kq, int KS, int hl,
                                       int ln31, const bf16x8& PF,
                                       f32x16& o0, f32x16& o1)
{
  const int vchunk = (kq << 2) + 2 * KS + hl;
  bf16x8 vf0 = *(const bf16x8*)&Vs[ln31 * 128 + ((vchunk ^ (ln31 & 15)) << 3)];
  bf16x8 vf1 = *(const bf16x8*)&Vs[(32 + ln31) * 128 +
                                   ((vchunk ^ ((32 + ln31) & 15)) << 3)];
  o0 = __builtin_amdgcn_mfma_f32_32x32x16_bf16(PF, vf0, o0, 0, 0, 0);
  o1 = __builtin_amdgcn_mfma_f32_32x32x16_bf16(PF, vf1, o1, 0, 0, 0);
}

// ---------------------------------------------------------------------------
// Flash attention v12 — R5 structure with the launch_bounds bug fixed.
// R5 post-mortem: __launch_bounds__ 2nd arg is CUDA-style min-BLOCKS/CU on
// this toolchain (R1 (512,4)->60 VGPR and R5 (1024,8)->32 VGPR both fit that
// model). (1024,8) demanded 128 waves/CU -> VGPR clamped to 32 -> total
// scratch spill (FETCH 360 MB). Correct bound for 2 blocks x 16 waves =
// 32 waves/CU (hw max) is (1024, 2) -> VGPR budget 64, which the per-wave
// code (strict subset of R1's 60-VGPR loop) fits.
// Same grid (512), same staging bytes/CU, same LDS (48 KB) — concurrency
// doubles with zero added traffic.
// ---------------------------------------------------------------------------
__global__ __launch_bounds__(1024, 2) void attn_kernel(
    const __bf16* __restrict__ Qb, const __bf16* __restrict__ Kb,
    const __bf16* __restrict__ Vtb, __bf16* __restrict__ Ob)
{
  __shared__ __align__(16) __bf16 smem[3 * 128 * 64];   // 48 KB
  __bf16* QP = smem;            // Q tile [q128][dk64]
  __bf16* Ks = smem + 8192;     // K tile [key128][dk64]
  __bf16* Vs = smem + 16384;    // V tile [d64][key128]

  const int t = threadIdx.x, w = t >> 6, lane = t & 63;
  const int ln31 = lane & 31, hl = lane >> 5;
  const int qg = w & 3;         // q-group (32 rows of the 128-q tile)
  const int kq = w >> 2;        // key-quarter (32 keys) of the staged tile
  const int bh = blockIdx.x;    // b*NHEAD + h  (XCD-locality key)
  const int q0 = blockIdx.y * 128;
  const int bb = bh >> 4, hh = bh & 15;

  const __bf16* Qg = Qb + (size_t)bh * SEQ * DKH + (size_t)q0 * DKH;
  const __bf16* Kg = Kb + (size_t)bh * SEQ * DKH;
  const __bf16* Vg = Vtb + (size_t)bh * DKH * SEQ;

  // stage Q tile: 1024 chunks / 1024 threads = 1 issue
  {
    const int c = t;
    const int row = c >> 3;                         // 8 chunks per 64-elem row
    const int goff = ((c & 7) ^ (row & 7)) << 3;
    async16(Qg + (size_t)row * DKH + goff, QP + c * 8);
  }
  __syncthreads();

  // Q B-fragments for this wave's 32 q-rows (held in regs for whole kernel)
  const int qrow = (qg << 5) + ln31;
  bf16x8 qf[4];
#pragma unroll
  for (int ks = 0; ks < 4; ++ks) {
    const int chunk = ((2 * ks + hl) ^ (qrow & 7));
    qf[ks] = *(const bf16x8*)&QP[qrow * 64 + (chunk << 3)];
  }

  float l_lane = 0.f;          // partial row-sum for q-row `qrow` (this quarter)
  f32x16 o0, o1;               // partial O[32q][64d]: d-blocks 0/1; d = db*32+ln31
#pragma unroll
  for (int r = 0; r < 16; ++r) { o0[r] = 0.f; o1[r] = 0.f; }

  for (int kt = 0; kt < SEQ; kt += 128) {
    __syncthreads();   // prior tile's Ks/Vs reads done; iter 0: Q reads done
    {
      const int c = t;
      // K [128 keys][64 dk]: 8 chunks/row — 1024 chunks / 1024 threads
      const int krow = c >> 3;
      const int kgoff = ((c & 7) ^ (krow & 7)) << 3;
      async16(Kg + (size_t)(kt + krow) * DKH + kgoff, Ks + c * 8);
      // V [64 d][128 keys]: 16 chunks/row — 1024 chunks / 1024 threads
      const int vrow = c >> 4;
      const int vgoff = ((c & 15) ^ (vrow & 15)) << 3;
      async16(Vg + (size_t)vrow * SEQ + kt + vgoff, Vs + c * 8);
    }
    __syncthreads();   // staging drain: Ks/Vs valid

    // ---- this wave's single 32-key block of the staged 128 ----
    f32x16 s;
#pragma unroll
    for (int r = 0; r < 16; ++r) s[r] = 0.f;
    const int kr = (kq << 5) + ln31;
    __builtin_amdgcn_s_setprio(1);
#pragma unroll
    for (int ks = 0; ks < 4; ++ks) {
      bf16x8 kf = *(const bf16x8*)&Ks[kr * 64 + (((2 * ks + hl) ^ (kr & 7)) << 3)];
      s = __builtin_amdgcn_mfma_f32_32x32x16_bf16(kf, qf[ks], s, 0, 0, 0);
    }
    __builtin_amdgcn_s_setprio(0);
    bf16x8 pa, pb;
    softmax_frag(s, l_lane, pa, pb);
    __builtin_amdgcn_s_setprio(1);
    pvstep(Vs, kq, 0, hl, ln31, pa, o0, o1);
    pvstep(Vs, kq, 1, hl, ln31, pb, o0, o1);
    __builtin_amdgcn_s_setprio(0);
  }

  // ---- cross-wave combine: 4 waves (kq 0..3) share each q-group.
  // 3 rounds: waves kq==r dump partial O (8 KB per qg) + l into dead LDS;
  // kq==0 accumulates. Round regions: 4 qg x 8 KB = 32 KB (QP+Ks, dead).
  __syncthreads();                       // all Ks/Vs LDS reads done
  float* cmb = (float*)smem;             // per-qg region: [d64][q32] f32
  const int dsw = ln31 & 7;
  l_lane += __shfl_xor(l_lane, 32);      // merge hl halves (same q-row)

#pragma unroll
  for (int r = 1; r < 4; ++r) {
    if (kq == r) {
      float* base = cmb + (qg << 11);
#pragma unroll
      for (int gg = 0; gg < 4; ++gg) {
        const int qq = ((2 * gg + hl) ^ dsw) << 2;   // swizzled q-quad slot
        f32x4 va, vb;
#pragma unroll
        for (int rr = 0; rr < 4; ++rr) { va[rr] = o0[4 * gg + rr]; vb[rr] = o1[4 * gg + rr]; }
        *(f32x4*)&base[ln31 * 32 + qq]        = va;   // d = ln31
        *(f32x4*)&base[(32 + ln31) * 32 + qq] = vb;   // d = 32+ln31
      }
      if (hl == 0) cmb[8192 + (qg << 5) + ln31] = l_lane;   // l region (Vs)
    }
    __syncthreads();
    if (kq == 0) {
      float* base = cmb + (qg << 11);
#pragma unroll
      for (int gg = 0; gg < 4; ++gg) {
        const int qq = ((2 * gg + hl) ^ dsw) << 2;
        const f32x4 va = *(const f32x4*)&base[ln31 * 32 + qq];
        const f32x4 vb = *(const f32x4*)&base[(32 + ln31) * 32 + qq];
#pragma unroll
        for (int rr = 0; rr < 4; ++rr) { o0[4 * gg + rr] += va[rr]; o1[4 * gg + rr] += vb[rr]; }
      }
      l_lane += cmb[8192 + (qg << 5) + ln31];
    }
    __syncthreads();
  }

  if (kq == 0) {
    const float inv = 1.0f / l_lane;

    // epilogue: O[b, q, h*64+d]; lane = d col; fetch inv via shfl
#pragma unroll
    for (int r = 0; r < 16; ++r) {
      const int qi = (r & 3) + 8 * (r >> 2) + 4 * hl;    // q within wave's 32
      const float iq = __shfl(inv, qi);                  // from lane qi (hl=0 half)
      const int q = q0 + (qg << 5) + qi;
      __bf16* rowp = Ob + ((size_t)(bb * SEQ + q)) * DMODEL + hh * DKH;
      rowp[ln31]      = (__bf16)(o0[r] * iq);
      rowp[32 + ln31] = (__bf16)(o1[r] * iq);
    }
  }
}

// ---------------------------------------------------------------------------
extern "C" void kernel_launch(void* const* d_in, const int* in_sizes, int n_in,
                              void* d_out, int out_size, void* d_ws, size_t ws_size,
                              hipStream_t stream)
{
  const float* x  = (const float*)d_in[0];
  const float* Wq = (const float*)d_in[1];
  const float* bq = (const float*)d_in[2];
  const float* Wk = (const float*)d_in[3];
  const float* bk = (const float*)d_in[4];
  const float* Wv = (const float*)d_in[5];
  const float* bv = (const float*)d_in[6];
  const float* Wo = (const float*)d_in[7];
  const float* bo = (const float*)d_in[8];
  float*  out = (float*)d_out;
  __bf16* ws  = (__bf16*)d_ws;

  // fp32 -> bf16 for x and the 4 weight matrices (one launch)
  cvt_fp32_bf16<<<dim3(2048, 5, 1), 256, 0, stream>>>(x, Wq, Wk, Wv, Wo, ws);

  // Q,K,V projections (fused, grid.z picks the matrix)
  qkv_gemm<<<dim3(MTOT / 128, DMODEL / 128, 3), 256, 0, stream>>>(
      ws + XB, ws + WQB, bq, ws + WKB, bk, ws + WVB, bv, ws);

  // flash attention: (bh, q-tile of 128) = 512 blocks x 1024 threads
  attn_kernel<<<dim3(BATCH * NHEAD, SEQ / 128), 1024, 0, stream>>>(
      ws + QOFF, ws + KOFF, ws + VOFF, ws + OOFF);

  // output projection -> fp32 d_out (64x128 tiles, 512 blocks)
  out_gemm<<<dim3(MTOT / 64, DMODEL / 128), 256, 0, stream>>>(
      ws + OOFF, ws + WOB, bo, out);
}

// Round 7
// 187.104 us; speedup vs baseline: 1.4136x; 1.0452x over previous
//
#include <hip/hip_runtime.h>

// ---------- problem constants ----------
#define BATCH   2
#define SEQ     2048
#define DMODEL  1024
#define NHEAD   16
#define DKH     64
#define MTOT    (BATCH*SEQ)      // 4096 rows for the projection GEMMs
#define KDIM    DMODEL           // 1024 contraction for projections

// ws layout in bf16 elements (total 24M bf16 = 48 MB)
#define XB    0u                     // x bf16            [4096,1024]  4M
#define WQB   (4u*1024u*1024u)       // Wq bf16           [1024,1024]  1M
#define WKB   (5u*1024u*1024u)
#define WVB   (6u*1024u*1024u)
#define WOB   (7u*1024u*1024u)
#define QOFF  (8u*1024u*1024u)       // Q  [B,H,N,dk] (pre-scaled log2e/8) 4M
#define KOFF  (12u*1024u*1024u)      // K  [B,H,N,dk]                  4M
#define VOFF  (16u*1024u*1024u)      // V^T [B,H,dk,N]                 4M
#define OOFF  (20u*1024u*1024u)      // attn out, flat [B,N,D]         4M

typedef __bf16 bf16x8 __attribute__((ext_vector_type(8)));
typedef __bf16 bf16x4 __attribute__((ext_vector_type(4)));
typedef float  f32x4  __attribute__((ext_vector_type(4)));
typedef float  f32x16 __attribute__((ext_vector_type(16)));

// async global->LDS, 16B per lane; LDS dest is wave-uniform base (HW adds lane*16)
__device__ __forceinline__ void async16(const __bf16* g, __bf16* l) {
  __builtin_amdgcn_global_load_lds(
      (const __attribute__((address_space(1))) void*)g,
      (__attribute__((address_space(3))) void*)l, 16, 0, 0);
}

// packed f32x2 -> bf16x2 (dword): lo in low 16 bits (T12 recipe, no builtin)
__device__ __forceinline__ unsigned cvtpk_bf16(float lo, float hi) {
  unsigned r;
  asm("v_cvt_pk_bf16_f32 %0, %1, %2" : "=v"(r) : "v"(lo), "v"(hi));
  return r;
}
// v_permlane32_swap_b32: a.hi32lanes <-> b.lo32lanes
__device__ __forceinline__ void plswap(unsigned& a, unsigned& b) {
  asm("v_permlane32_swap_b32 %0, %1" : "+v"(a), "+v"(b));
}

// ---------------------------------------------------------------------------
// fp32 -> bf16 conversion: blockIdx.y selects tensor (0:x, 1..4:Wq/Wk/Wv/Wo)
// ---------------------------------------------------------------------------
__global__ __launch_bounds__(256) void cvt_fp32_bf16(
    const float* __restrict__ x,  const float* __restrict__ wq,
    const float* __restrict__ wk, const float* __restrict__ wv,
    const float* __restrict__ wo, __bf16* __restrict__ ws)
{
  const float* src; __bf16* dst; int n;
  switch (blockIdx.y) {
    case 0:  src = x;  dst = ws + XB;  n = 4 * 1024 * 1024; break;
    case 1:  src = wq; dst = ws + WQB; n = 1024 * 1024;     break;
    case 2:  src = wk; dst = ws + WKB; n = 1024 * 1024;     break;
    case 3:  src = wv; dst = ws + WVB; n = 1024 * 1024;     break;
    default: src = wo; dst = ws + WOB; n = 1024 * 1024;     break;
  }
  const int i = (blockIdx.x * 256 + threadIdx.x) * 8;
  if (i < n) {
    const float4 a = *(const float4*)(src + i);
    const float4 b = *(const float4*)(src + i + 4);
    bf16x8 o;
    o[0] = (__bf16)a.x; o[1] = (__bf16)a.y; o[2] = (__bf16)a.z; o[3] = (__bf16)a.w;
    o[4] = (__bf16)b.x; o[5] = (__bf16)b.y; o[6] = (__bf16)b.z; o[7] = (__bf16)b.w;
    *(bf16x8*)(dst + i) = o;
  }
}

// ---------------------------------------------------------------------------
// 128x128 NT-GEMM core, BK=32 (single-buffer — R2 showed explicit dbuf is
// net-negative here). lds: A-tile [0,4096), B-tile [4096,8192) (16 KB).
// 16B-chunk XOR swizzle: chunk' = chunk ^ (row & 3).
// ---------------------------------------------------------------------------
__device__ __forceinline__ void gemm128_core(
    const __bf16* __restrict__ A, const __bf16* __restrict__ W,
    int m0, int n0, __bf16* lds, f32x4 (&acc)[4][4])
{
  __bf16* A_lds = lds;
  __bf16* B_lds = lds + 4096;
  const int t    = threadIdx.x;
  const int w    = t >> 6;
  const int lane = t & 63;
  const int ln15 = lane & 15;
  const int quad = lane >> 4;
  const int wr   = (w >> 1) << 6;   // wave row offset within 128
  const int wc   = (w & 1) << 6;    // wave col offset within 128

#pragma unroll
  for (int i = 0; i < 4; ++i)
#pragma unroll
    for (int j = 0; j < 4; ++j) acc[i][j] = (f32x4){0.f, 0.f, 0.f, 0.f};

  for (int kt = 0; kt < KDIM; kt += 32) {
    __syncthreads();   // previous tile's LDS reads done
#pragma unroll
    for (int issue = 0; issue < 2; ++issue) {
      const int cbase = issue * 256 + (w << 6);
      const int c     = cbase + lane;
      const int row   = c >> 2;                       // 4 chunks (32 bf16) per row
      const int goff  = ((c & 3) ^ (row & 3)) << 3;   // swizzled source chunk
      async16(A + (size_t)(m0 + row) * KDIM + kt + goff, A_lds + cbase * 8);
      async16(W + (size_t)(n0 + row) * KDIM + kt + goff, B_lds + cbase * 8);
    }
    __syncthreads();   // vmcnt(0) drain: LDS tiles valid

    bf16x8 af[4], bfr[4];
#pragma unroll
    for (int i = 0; i < 4; ++i) {
      const int row = wr + i * 16 + ln15;
      af[i] = *(const bf16x8*)&A_lds[row * 32 + ((quad ^ (row & 3)) << 3)];
    }
#pragma unroll
    for (int j = 0; j < 4; ++j) {
      const int row = wc + j * 16 + ln15;
      bfr[j] = *(const bf16x8*)&B_lds[row * 32 + ((quad ^ (row & 3)) << 3)];
    }
#pragma unroll
    for (int i = 0; i < 4; ++i)
#pragma unroll
      for (int j = 0; j < 4; ++j)
        acc[i][j] = __builtin_amdgcn_mfma_f32_16x16x32_bf16(af[i], bfr[j], acc[i][j], 0, 0, 0);
  }
}

// ---------------------------------------------------------------------------
// Fused QKV projection: z=0 -> Q (scaled log2e/8) [B,H,N,dk]; z=1 -> K;
// z=2 -> V transposed [B,H,dk,N]. Biases fp32. 16B vectorized stores via
// per-wave LDS repack.
// ---------------------------------------------------------------------------
__global__ __launch_bounds__(256) void qkv_gemm(
    const __bf16* __restrict__ X,
    const __bf16* __restrict__ Wq, const float* __restrict__ bq,
    const __bf16* __restrict__ Wk, const float* __restrict__ bk,
    const __bf16* __restrict__ Wv, const float* __restrict__ bv,
    __bf16* __restrict__ ws)
{
  __shared__ __align__(16) __bf16 lds[128 * 64];   // 16 KB

  const int z = blockIdx.z;
  const __bf16* W    = (z == 0) ? Wq : (z == 1) ? Wk : Wv;
  const float*  bias = (z == 0) ? bq : (z == 1) ? bk : bv;
  __bf16* out = ws + ((z == 0) ? QOFF : (z == 1) ? KOFF : VOFF);
  // softmax runs in exp2 domain: fold 1/sqrt(dk) * log2(e) into Q
  const float scale = (z == 0) ? 0.125f * 1.44269504088896f : 1.0f;

  const int m0 = blockIdx.x * 128;
  const int n0 = blockIdx.y * 128;

  f32x4 acc[4][4];
  gemm128_core(X, W, m0, n0, lds, acc);

  const int t = threadIdx.x, w = t >> 6, lane = t & 63;
  const int ln15 = lane & 15, quad = lane >> 4;
  const int wr = (w >> 1) << 6, wc = (w & 1) << 6;

  // bias values for this wave's 64 columns (col = j*16+ln15)
  float bj4[4];
#pragma unroll
  for (int j = 0; j < 4; ++j) bj4[j] = bias[n0 + wc + j * 16 + ln15];

  __syncthreads();                     // all waves done reading K-tiles
  __bf16* scr = lds + (w << 10);       // per-wave 1024-elem scratch (2 KB)

  const int bb = m0 >> 11;             // batch (blocks never straddle)
  const int s_base = (m0 & 2047) + wr;
  const int h = (n0 + wc) >> 6;

  if (z != 2) {
    // ---- Q/K [B,H,N,dk]: row-major scratch [row16][d64], coalesced stores
    const int rdrow = lane & 15, rdseg = lane >> 4;
#pragma unroll
    for (int i = 0; i < 4; ++i) {
#pragma unroll
      for (int j = 0; j < 4; ++j)
#pragma unroll
        for (int rr = 0; rr < 4; ++rr)
          scr[(quad * 4 + rr) * 64 + j * 16 + ln15] =
              (__bf16)((acc[i][j][rr] + bj4[j]) * scale);
      // wave-private scratch: compiler orders via lgkmcnt, no barrier
      bf16x8 v0 = *(const bf16x8*)&scr[rdrow * 64 + rdseg * 16];
      bf16x8 v1 = *(const bf16x8*)&scr[rdrow * 64 + rdseg * 16 + 8];
      const int s = s_base + i * 16 + rdrow;
      __bf16* p = out + (((size_t)(bb * NHEAD + h)) * SEQ + s) * DKH + rdseg * 16;
      *(bf16x8*)p = v0;
      *(bf16x8*)&p[8] = v1;
    }
  } else {
    // ---- V^T [B,H,dk,N]: col-major scratch [d64][row16] does the transpose;
    // each lane then stores 32B contiguous in s.
#pragma unroll
    for (int i = 0; i < 4; ++i) {
#pragma unroll
      for (int j = 0; j < 4; ++j) {
        bf16x4 pk;
#pragma unroll
        for (int rr = 0; rr < 4; ++rr) pk[rr] = (__bf16)(acc[i][j][rr] + bj4[j]);
        *(bf16x4*)&scr[(j * 16 + ln15) * 16 + quad * 4] = pk;
      }
      bf16x8 c0 = *(const bf16x8*)&scr[lane * 16];
      bf16x8 c1 = *(const bf16x8*)&scr[lane * 16 + 8];
      __bf16* p = out + (((size_t)(bb * NHEAD + h)) * DKH + lane) * SEQ
                      + s_base + i * 16;
      *(bf16x8*)p = c0;
      *(bf16x8*)&p[8] = c1;
    }
  }
}

// ---------------------------------------------------------------------------
// Output projection: d_out(fp32) = O[M,K]bf16 @ Wo[N,K]bf16^T + bo(fp32).
// 64x128 tile -> 512 blocks (2/CU). 4 waves, each 64 rows x 32 cols.
// ---------------------------------------------------------------------------
__global__ __launch_bounds__(256) void out_gemm(
    const __bf16* __restrict__ A, const __bf16* __restrict__ Wo,
    const float* __restrict__ bo, float* __restrict__ out)
{
  __shared__ __align__(16) __bf16 lds[6144];   // A 64x32 | B 128x32 (12 KB)
  __bf16* A_lds = lds;
  __bf16* B_lds = lds + 2048;

  const int m0 = blockIdx.x * 64;
  const int n0 = blockIdx.y * 128;

  const int t = threadIdx.x, w = t >> 6, lane = t & 63;
  const int ln15 = lane & 15, quad = lane >> 4;

  f32x4 acc[4][2];
#pragma unroll
  for (int i = 0; i < 4; ++i)
#pragma unroll
    for (int j = 0; j < 2; ++j) acc[i][j] = (f32x4){0.f, 0.f, 0.f, 0.f};

  for (int kt = 0; kt < KDIM; kt += 32) {
    __syncthreads();
    {  // A: 64 rows x 4 chunks = 256 chunks = 1 issue
      const int c = (w << 6) + lane;
      const int row = c >> 2;
      const int goff = ((c & 3) ^ (row & 3)) << 3;
      async16(A + (size_t)(m0 + row) * KDIM + kt + goff, A_lds + c * 8);
    }
#pragma unroll
    for (int issue = 0; issue < 2; ++issue) {  // B: 128 rows x 4 chunks = 2 issues
      const int cbase = issue * 256 + (w << 6);
      const int c = cbase + lane;
      const int row = c >> 2;
      const int goff = ((c & 3) ^ (row & 3)) << 3;
      async16(Wo + (size_t)(n0 + row) * KDIM + kt + goff, B_lds + cbase * 8);
    }
    __syncthreads();

    bf16x8 af[4], bfr[2];
#pragma unroll
    for (int i = 0; i < 4; ++i) {
      const int row = i * 16 + ln15;
      af[i] = *(const bf16x8*)&A_lds[row * 32 + ((quad ^ (row & 3)) << 3)];
    }
#pragma unroll
    for (int j = 0; j < 2; ++j) {
      const int row = (w << 5) + j * 16 + ln15;
      bfr[j] = *(const bf16x8*)&B_lds[row * 32 + ((quad ^ (row & 3)) << 3)];
    }
#pragma unroll
    for (int i = 0; i < 4; ++i)
#pragma unroll
      for (int j = 0; j < 2; ++j)
        acc[i][j] = __builtin_amdgcn_mfma_f32_16x16x32_bf16(af[i], bfr[j], acc[i][j], 0, 0, 0);
  }

  float bj2[2];
#pragma unroll
  for (int j = 0; j < 2; ++j) bj2[j] = bo[n0 + (w << 5) + j * 16 + ln15];

  __syncthreads();                          // waves done reading A/B tiles
  float* scrf = (float*)lds + (w << 9);     // per-wave 512-float scratch (2 KB)

  const int rdrow = lane & 15, rdseg = lane >> 4;
#pragma unroll
  for (int i = 0; i < 4; ++i) {
#pragma unroll
    for (int j = 0; j < 2; ++j) {
      f32x4 v;
#pragma unroll
      for (int rr = 0; rr < 4; ++rr) v[rr] = acc[i][j][rr] + bj2[j];
      *(f32x4*)&scrf[(j * 16 + ln15) * 16 + quad * 4] = v;   // col-major
    }
    const int m = m0 + i * 16 + rdrow;
    float* p = out + (size_t)m * DMODEL + n0 + (w << 5) + rdseg * 8;
#pragma unroll
    for (int cc = 0; cc < 2; ++cc) {
      f32x4 v;
#pragma unroll
      for (int e = 0; e < 4; ++e)
        v[e] = scrf[(rdseg * 8 + cc * 4 + e) * 16 + rdrow];
      *(f32x4*)&p[cc * 4] = v;
    }
  }
}

// ---------------------------------------------------------------------------
// softmax fragment build (T12): s holds S^T regs for one 32-key block
// (key = (r&3) + 8*(r>>2) + 4*hl, q = ln31). exp2 in place, then
// cvt_pk pairs + permlane32_swap reassemble the PV A-fragments entirely
// in registers — no P LDS round-trip.
// ---------------------------------------------------------------------------
__device__ __forceinline__ void softmax_frag(const f32x16& s, float& l,
                                             bf16x8& pfa, bf16x8& pfb)
{
  float p[16];
#pragma unroll
  for (int r = 0; r < 16; ++r) {
    p[r] = __builtin_amdgcn_exp2f(s[r]);
    l += p[r];
  }
  unsigned A0 = cvtpk_bf16(p[0],  p[1]);   // (0,1)   | (4,5)
  unsigned A1 = cvtpk_bf16(p[2],  p[3]);   // (2,3)   | (6,7)
  unsigned B0 = cvtpk_bf16(p[4],  p[5]);   // (8,9)   | (12,13)
  unsigned B1 = cvtpk_bf16(p[6],  p[7]);   // (10,11) | (14,15)
  unsigned C0 = cvtpk_bf16(p[8],  p[9]);   // (16,17) | (20,21)
  unsigned C1 = cvtpk_bf16(p[10], p[11]);  // (18,19) | (22,23)
  unsigned D0 = cvtpk_bf16(p[12], p[13]);  // (24,25) | (28,29)
  unsigned D1 = cvtpk_bf16(p[14], p[15]);  // (26,27) | (30,31)
  plswap(A0, B0);
  plswap(A1, B1);
  plswap(C0, D0);
  plswap(C1, D1);
  union { unsigned u[4]; bf16x8 v; } ua, ub;
  ua.u[0] = A0; ua.u[1] = A1; ua.u[2] = B0; ua.u[3] = B1;  // k 0..7 | 8..15
  ub.u[0] = C0; ub.u[1] = C1; ub.u[2] = D0; ub.u[3] = D1;  // k 16..23 | 24..31
  pfa = ua.v;
  pfb = ub.v;
}

// ---------------------------------------------------------------------------
// PV step: A-frag PF covers keys kh*64 + KS*16 + hl*8 .. +8
// ---------------------------------------------------------------------------
__device__ __forceinline__ void pvstep(const __bf16* Vs, int kh, int KS, int hl,
                                       int ln31, const bf16x8& PF,
                                       f32x16& o0, f32x16& o1)
{
  const int vchunk = (kh << 3) + 2 * KS + hl;
  bf16x8 vf0 = *(const bf16x8*)&Vs[ln31 * 128 + ((vchunk ^ (ln31 & 15)) << 3)];
  bf16x8 vf1 = *(const bf16x8*)&Vs[(32 + ln31) * 128 +
                                   ((vchunk ^ ((32 + ln31) & 15)) << 3)];
  o0 = __builtin_amdgcn_mfma_f32_32x32x16_bf16(PF, vf0, o0, 0, 0, 0);
  o1 = __builtin_amdgcn_mfma_f32_32x32x16_bf16(PF, vf1, o1, 0, 0, 0);
}

// per-128-key-tile compute for one wave (its 64-key half, two 32-key blocks)
// — R1-verified serial order.
__device__ __forceinline__ void attn_tile_compute(
    const __bf16* Ks, const __bf16* Vs, const bf16x8 (&qf)[4],
    int kh, int ln31, int hl, float& l_lane, f32x16& o0, f32x16& o1)
{
#pragma unroll
  for (int half = 0; half < 2; ++half) {
    f32x16 s;
#pragma unroll
    for (int r = 0; r < 16; ++r) s[r] = 0.f;
    const int kr = (kh << 6) + half * 32 + ln31;
    __builtin_amdgcn_s_setprio(1);
#pragma unroll
    for (int ks = 0; ks < 4; ++ks) {
      bf16x8 kf = *(const bf16x8*)&Ks[kr * 64 + (((2 * ks + hl) ^ (kr & 7)) << 3)];
      s = __builtin_amdgcn_mfma_f32_32x32x16_bf16(kf, qf[ks], s, 0, 0, 0);
    }
    __builtin_amdgcn_s_setprio(0);
    bf16x8 pa, pb;
    softmax_frag(s, l_lane, pa, pb);
    __builtin_amdgcn_s_setprio(1);
    pvstep(Vs, kh, half * 2 + 0, hl, ln31, pa, o0, o1);
    pvstep(Vs, kh, half * 2 + 1, hl, ln31, pb, o0, o1);
    __builtin_amdgcn_s_setprio(0);
  }
}

// ---------------------------------------------------------------------------
// Flash attention v13 — R1 structure (verified best: 44.4 µs) + T14
// async-STAGE split (reg-staged K/V). R6's key-split x4 reverted (per-wave
// work per barrier halved -> lockstep overhead fraction doubled; R1's 8-wave
// geometry is the optimum of that lever).
// T14: load K/V tile t+1 into REGISTERS during tile-t compute (compute phase
// has no vmem dependence -> no vmcnt drain blocks it), then after the
// barrier only a cheap ds_write regs->LDS is exposed. Byte-exact same LDS
// image as gload_lds (per-thread dest Ks + c*16B == uniform-base + lane*16).
// +16 VGPR staging state -> __launch_bounds__(512, 2) (128-VGPR class;
// occupancy unchanged: grid is the binding 2 blocks/CU = 16 waves/CU).
// ---------------------------------------------------------------------------
__global__ __launch_bounds__(512, 2) void attn_kernel(
    const __bf16* __restrict__ Qb, const __bf16* __restrict__ Kb,
    const __bf16* __restrict__ Vtb, __bf16* __restrict__ Ob)
{
  __shared__ __align__(16) __bf16 smem[3 * 128 * 64];   // 48 KB
  __bf16* QP = smem;            // Q tile [q128][dk64]
  __bf16* Ks = smem + 8192;     // K tile [key128][dk64]
  __bf16* Vs = smem + 16384;    // V tile [d64][key128]

  const int t = threadIdx.x, w = t >> 6, lane = t & 63;
  const int ln31 = lane & 31, hl = lane >> 5;
  const int g  = w & 3;         // q-group (32 rows of the 128-q tile)
  const int kh = w >> 2;        // key-half (64 keys) of the staged tile
  const int bh = blockIdx.x;    // b*NHEAD + h  (XCD-locality key)
  const int q0 = blockIdx.y * 128;
  const int bb = bh >> 4, hh = bh & 15;

  const __bf16* Qg = Qb + (size_t)bh * SEQ * DKH + (size_t)q0 * DKH;
  const __bf16* Kg = Kb + (size_t)bh * SEQ * DKH;
  const __bf16* Vg = Vtb + (size_t)bh * DKH * SEQ;

  // stage Q tile (128x64 = 1024 chunks / 512 threads = 2 issues, gload_lds)
#pragma unroll
  for (int issue = 0; issue < 2; ++issue) {
    const int cbase = issue * 512 + (w << 6);
    const int c = cbase + lane;
    const int row = c >> 3;                         // 8 chunks per 64-elem row
    const int goff = ((c & 7) ^ (row & 7)) << 3;
    async16(Qg + (size_t)row * DKH + goff, QP + cbase * 8);
  }

  // ---- T14 staging geometry (per-thread, constant) ----
  // chunk ids c0 = t, c1 = t+512 replicate R1's (issue*512 + w*64 + lane).
  const int c0 = t, c1 = t + 512;
  const int krow0 = c0 >> 3; const int kgo0 = ((c0 & 7) ^ (krow0 & 7)) << 3;
  const int krow1 = c1 >> 3; const int kgo1 = ((c1 & 7) ^ (krow1 & 7)) << 3;
  const int vrow0 = c0 >> 4; const int vgo0 = ((c0 & 15) ^ (vrow0 & 15)) << 3;
  const int vrow1 = c1 >> 4; const int vgo1 = ((c1 & 15) ^ (vrow1 & 15)) << 3;
  const __bf16* kp0 = Kg + (size_t)krow0 * DKH + kgo0;   // + kt*DKH per tile
  const __bf16* kp1 = Kg + (size_t)krow1 * DKH + kgo1;
  const __bf16* vp0 = Vg + (size_t)vrow0 * SEQ + vgo0;   // + kt per tile
  const __bf16* vp1 = Vg + (size_t)vrow1 * SEQ + vgo1;
  __bf16* kd0 = Ks + c0 * 8;  __bf16* kd1 = Ks + c1 * 8;
  __bf16* vd0 = Vs + c0 * 8;  __bf16* vd1 = Vs + c1 * 8;

  // issue tile-0 K/V loads into regs (overlaps Q staging + frag setup)
  bf16x8 krg0 = *(const bf16x8*)kp0;
  bf16x8 krg1 = *(const bf16x8*)kp1;
  bf16x8 vrg0 = *(const bf16x8*)vp0;
  bf16x8 vrg1 = *(const bf16x8*)vp1;

  __syncthreads();   // Q tile valid

  // Q B-fragments for this wave's 32 q-rows (held in regs for whole kernel)
  const int qrow = (g << 5) + ln31;
  bf16x8 qf[4];
#pragma unroll
  for (int ks = 0; ks < 4; ++ks) {
    const int chunk = ((2 * ks + hl) ^ (qrow & 7));
    qf[ks] = *(const bf16x8*)&QP[qrow * 64 + (chunk << 3)];
  }

  float l_lane = 0.f;          // partial row-sum for q-row `qrow` (this key-half)
  f32x16 o0, o1;               // partial O[32q][64d]: d-blocks 0/1; d = db*32+ln31
#pragma unroll
  for (int r = 0; r < 16; ++r) { o0[r] = 0.f; o1[r] = 0.f; }

  for (int kt = 0; kt < SEQ; kt += 128) {
    __syncthreads();   // prior tile's Ks/Vs reads done; iter 0: Q reads done
    // write current tile's regs -> LDS (only exposed staging cost)
    *(bf16x8*)kd0 = krg0;  *(bf16x8*)kd1 = krg1;
    *(bf16x8*)vd0 = vrg0;  *(bf16x8*)vd1 = vrg1;
    __syncthreads();   // Ks/Vs valid
    if (kt + 128 < SEQ) {
      // issue next tile's loads; latency hides under this tile's compute
      krg0 = *(const bf16x8*)(kp0 + (size_t)(kt + 128) * DKH);
      krg1 = *(const bf16x8*)(kp1 + (size_t)(kt + 128) * DKH);
      vrg0 = *(const bf16x8*)(vp0 + kt + 128);
      vrg1 = *(const bf16x8*)(vp1 + kt + 128);
    }
    attn_tile_compute(Ks, Vs, qf, kh, ln31, hl, l_lane, o0, o1);
  }

  // ---- cross-wave combine: pair (w, w+4) holds same q-rows, disjoint keys.
  // Waves 4..7 dump partial O (8 KB each) + l into dead Q/K LDS; waves
  // 0..3 sum, normalize, store.
  __syncthreads();                       // all Ks/Vs LDS reads done
  float* cmb = (float*)smem;             // pair region: [d64][q32] f32
  const int dsw = ln31 & 7;
  l_lane += __shfl_xor(l_lane, 32);      // both key-sub-blocks of this wave

  if (w >= 4) {
    float* base = cmb + (g << 11);
#pragma unroll
    for (int gg = 0; gg < 4; ++gg) {
      const int qq = ((2 * gg + hl) ^ dsw) << 2;   // swizzled q-quad slot
      f32x4 va, vb;
#pragma unroll
      for (int rr = 0; rr < 4; ++rr) { va[rr] = o0[4 * gg + rr]; vb[rr] = o1[4 * gg + rr]; }
      *(f32x4*)&base[ln31 * 32 + qq]        = va;   // d = ln31
      *(f32x4*)&base[(32 + ln31) * 32 + qq] = vb;   // d = 32+ln31
    }
    if (hl == 0) cmb[8192 + (g << 5) + ln31] = l_lane;   // l region
  }
  __syncthreads();
  if (w < 4) {
    float* base = cmb + (g << 11);
#pragma unroll
    for (int gg = 0; gg < 4; ++gg) {
      const int qq = ((2 * gg + hl) ^ dsw) << 2;
      const f32x4 va = *(const f32x4*)&base[ln31 * 32 + qq];
      const f32x4 vb = *(const f32x4*)&base[(32 + ln31) * 32 + qq];
#pragma unroll
      for (int rr = 0; rr < 4; ++rr) { o0[4 * gg + rr] += va[rr]; o1[4 * gg + rr] += vb[rr]; }
    }
    const float inv = 1.0f / (l_lane + cmb[8192 + (g << 5) + ln31]);

    // epilogue: O[b, q, h*64+d]; lane = d col; fetch inv via shfl
#pragma unroll
    for (int r = 0; r < 16; ++r) {
      const int qi = (r & 3) + 8 * (r >> 2) + 4 * hl;    // q within wave's 32
      const float iq = __shfl(inv, qi);                  // from lane qi (hl=0 half)
      const int q = q0 + (g << 5) + qi;
      __bf16* rowp = Ob + ((size_t)(bb * SEQ + q)) * DMODEL + hh * DKH;
      rowp[ln31]      = (__bf16)(o0[r] * iq);
      rowp[32 + ln31] = (__bf16)(o1[r] * iq);
    }
  }
}

// ---------------------------------------------------------------------------
extern "C" void kernel_launch(void* const* d_in, const int* in_sizes, int n_in,
                              void* d_out, int out_size, void* d_ws, size_t ws_size,
                              hipStream_t stream)
{
  const float* x  = (const float*)d_in[0];
  const float* Wq = (const float*)d_in[1];
  const float* bq = (const float*)d_in[2];
  const float* Wk = (const float*)d_in[3];
  const float* bk = (const float*)d_in[4];
  const float* Wv = (const float*)d_in[5];
  const float* bv = (const float*)d_in[6];
  const float* Wo = (const float*)d_in[7];
  const float* bo = (const float*)d_in[8];
  float*  out = (float*)d_out;
  __bf16* ws  = (__bf16*)d_ws;

  // fp32 -> bf16 for x and the 4 weight matrices (one launch)
  cvt_fp32_bf16<<<dim3(2048, 5, 1), 256, 0, stream>>>(x, Wq, Wk, Wv, Wo, ws);

  // Q,K,V projections (fused, grid.z picks the matrix)
  qkv_gemm<<<dim3(MTOT / 128, DMODEL / 128, 3), 256, 0, stream>>>(
      ws + XB, ws + WQB, bq, ws + WKB, bk, ws + WVB, bv, ws);

  // flash attention: (bh, q-tile of 128) = 512 blocks x 512 threads
  attn_kernel<<<dim3(BATCH * NHEAD, SEQ / 128), 512, 0, stream>>>(
      ws + QOFF, ws + KOFF, ws + VOFF, ws + OOFF);

  // output projection -> fp32 d_out (64x128 tiles, 512 blocks)
  out_gemm<<<dim3(MTOT / 64, DMODEL / 128), 256, 0, stream>>>(
      ws + OOFF, ws + WOB, bo, out);
}

// Round 8
// 182.490 us; speedup vs baseline: 1.4494x; 1.0253x over previous
//
#include <hip/hip_runtime.h>

// ---------- problem constants ----------
#define BATCH   2
#define SEQ     2048
#define DMODEL  1024
#define NHEAD   16
#define DKH     64
#define MTOT    (BATCH*SEQ)      // 4096 rows for the projection GEMMs
#define KDIM    DMODEL           // 1024 contraction for projections

// ws layout in bf16 elements (total 24M bf16 = 48 MB)
#define XB    0u                     // x bf16            [4096,1024]  4M
#define WQB   (4u*1024u*1024u)       // Wq bf16           [1024,1024]  1M
#define WKB   (5u*1024u*1024u)
#define WVB   (6u*1024u*1024u)
#define WOB   (7u*1024u*1024u)
#define QOFF  (8u*1024u*1024u)       // Q  [B,H,N,dk] (pre-scaled log2e/8) 4M
#define KOFF  (12u*1024u*1024u)      // K  [B,H,N,dk]                  4M
#define VOFF  (16u*1024u*1024u)      // V^T [B,H,dk,N]                 4M
#define OOFF  (20u*1024u*1024u)      // attn out, flat [B,N,D]         4M

typedef __bf16 bf16x8 __attribute__((ext_vector_type(8)));
typedef __bf16 bf16x4 __attribute__((ext_vector_type(4)));
typedef float  f32x4  __attribute__((ext_vector_type(4)));
typedef float  f32x16 __attribute__((ext_vector_type(16)));

// async global->LDS, 16B per lane; LDS dest is wave-uniform base (HW adds lane*16)
__device__ __forceinline__ void async16(const __bf16* g, __bf16* l) {
  __builtin_amdgcn_global_load_lds(
      (const __attribute__((address_space(1))) void*)g,
      (__attribute__((address_space(3))) void*)l, 16, 0, 0);
}

// counted waits (T4): compiler-level memory fence + hw wait, NO full drain.
#define VWAIT(N) asm volatile("s_waitcnt vmcnt(" #N ")" ::: "memory")

// packed f32x2 -> bf16x2 (dword): lo in low 16 bits (T12 recipe, no builtin)
__device__ __forceinline__ unsigned cvtpk_bf16(float lo, float hi) {
  unsigned r;
  asm("v_cvt_pk_bf16_f32 %0, %1, %2" : "=v"(r) : "v"(lo), "v"(hi));
  return r;
}
// v_permlane32_swap_b32: a.hi32lanes <-> b.lo32lanes
__device__ __forceinline__ void plswap(unsigned& a, unsigned& b) {
  asm("v_permlane32_swap_b32 %0, %1" : "+v"(a), "+v"(b));
}

// ---------------------------------------------------------------------------
// fp32 -> bf16 conversion: blockIdx.y selects tensor (0:x, 1..4:Wq/Wk/Wv/Wo)
// ---------------------------------------------------------------------------
__global__ __launch_bounds__(256) void cvt_fp32_bf16(
    const float* __restrict__ x,  const float* __restrict__ wq,
    const float* __restrict__ wk, const float* __restrict__ wv,
    const float* __restrict__ wo, __bf16* __restrict__ ws)
{
  const float* src; __bf16* dst; int n;
  switch (blockIdx.y) {
    case 0:  src = x;  dst = ws + XB;  n = 4 * 1024 * 1024; break;
    case 1:  src = wq; dst = ws + WQB; n = 1024 * 1024;     break;
    case 2:  src = wk; dst = ws + WKB; n = 1024 * 1024;     break;
    case 3:  src = wv; dst = ws + WVB; n = 1024 * 1024;     break;
    default: src = wo; dst = ws + WOB; n = 1024 * 1024;     break;
  }
  const int i = (blockIdx.x * 256 + threadIdx.x) * 8;
  if (i < n) {
    const float4 a = *(const float4*)(src + i);
    const float4 b = *(const float4*)(src + i + 4);
    bf16x8 o;
    o[0] = (__bf16)a.x; o[1] = (__bf16)a.y; o[2] = (__bf16)a.z; o[3] = (__bf16)a.w;
    o[4] = (__bf16)b.x; o[5] = (__bf16)b.y; o[6] = (__bf16)b.z; o[7] = (__bf16)b.w;
    *(bf16x8*)(dst + i) = o;
  }
}

// ---------------------------------------------------------------------------
// 128x128 NT-GEMM core — R8: TRIPLE-BUFFERED K-loop with counted vmcnt + raw
// s_barrier (T4). Why 3 slots: with one barrier per K-step, stage(tile i+2)
// into slot (i+2)%3 is safe because that slot was last READ at tile i-1's
// compute, which is separated by 2 barriers. Per step:
//   vmcnt(4)        — own tile-i loads landed (tile i+1's 4 stay in flight)
//   raw s_barrier   — all waves: tile-i in LDS AND tile-(i-1) reads done
//   stage(i+2)      — 4 gload_lds, fly across the next 2 barriers
//   compute(i)      — ds_read + 16 MFMA
// vs the old 2-barrier + __syncthreads() structure whose implicit
// vmcnt(0)-before-barrier drained every prefetch (R2/R7 failure mechanism).
// LDS: 3 slots x (A 4096 | B 4096) = 48 KB.
// ---------------------------------------------------------------------------
__device__ __forceinline__ void gemm_stage128(
    const __bf16* __restrict__ A, const __bf16* __restrict__ W,
    int m0, int n0, int kt, __bf16* slot, int w, int lane)
{
#pragma unroll
  for (int issue = 0; issue < 2; ++issue) {
    const int cbase = issue * 256 + (w << 6);
    const int c     = cbase + lane;
    const int row   = c >> 2;                       // 4 chunks (32 bf16) per row
    const int goff  = ((c & 3) ^ (row & 3)) << 3;   // swizzled source chunk
    async16(A + (size_t)(m0 + row) * KDIM + kt + goff, slot + cbase * 8);
    async16(W + (size_t)(n0 + row) * KDIM + kt + goff, slot + 4096 + cbase * 8);
  }
}

__device__ __forceinline__ void gemm_step128(
    const __bf16* slot, int wr, int wc, int ln15, int quad, f32x4 (&acc)[4][4])
{
  const __bf16* A_lds = slot;
  const __bf16* B_lds = slot + 4096;
  bf16x8 af[4], bfr[4];
#pragma unroll
  for (int i = 0; i < 4; ++i) {
    const int row = wr + i * 16 + ln15;
    af[i] = *(const bf16x8*)&A_lds[row * 32 + ((quad ^ (row & 3)) << 3)];
  }
#pragma unroll
  for (int j = 0; j < 4; ++j) {
    const int row = wc + j * 16 + ln15;
    bfr[j] = *(const bf16x8*)&B_lds[row * 32 + ((quad ^ (row & 3)) << 3)];
  }
#pragma unroll
  for (int i = 0; i < 4; ++i)
#pragma unroll
    for (int j = 0; j < 4; ++j)
      acc[i][j] = __builtin_amdgcn_mfma_f32_16x16x32_bf16(af[i], bfr[j], acc[i][j], 0, 0, 0);
}

__device__ __forceinline__ void gemm128_core(
    const __bf16* __restrict__ A, const __bf16* __restrict__ W,
    int m0, int n0, __bf16* lds, f32x4 (&acc)[4][4])
{
  const int t    = threadIdx.x;
  const int w    = t >> 6;
  const int lane = t & 63;
  const int ln15 = lane & 15;
  const int quad = lane >> 4;
  const int wr   = (w >> 1) << 6;   // wave row offset within 128
  const int wc   = (w & 1) << 6;    // wave col offset within 128

#pragma unroll
  for (int i = 0; i < 4; ++i)
#pragma unroll
    for (int j = 0; j < 4; ++j) acc[i][j] = (f32x4){0.f, 0.f, 0.f, 0.f};

  __bf16* s0 = lds;             // slot of tile i   (i%3==0)
  __bf16* s1 = lds + 8192;      // slot of tile i+1
  __bf16* s2 = lds + 16384;     // slot of tile i+2

  // prologue: tiles 0,1 in flight (8 outstanding loads/thread)
  gemm_stage128(A, W, m0, n0, 0,  s0, w, lane);
  gemm_stage128(A, W, m0, n0, 32, s1, w, lane);

  // main loop: tiles 0..29, 3-unrolled for static slot rotation
  int kt = 0;
#pragma unroll 1
  for (int i3 = 0; i3 < 10; ++i3) {
    VWAIT(4); __builtin_amdgcn_s_barrier();
    gemm_stage128(A, W, m0, n0, kt + 64, s2, w, lane);
    gemm_step128(s0, wr, wc, ln15, quad, acc);

    VWAIT(4); __builtin_amdgcn_s_barrier();
    gemm_stage128(A, W, m0, n0, kt + 96, s0, w, lane);
    gemm_step128(s1, wr, wc, ln15, quad, acc);

    VWAIT(4); __builtin_amdgcn_s_barrier();
    gemm_stage128(A, W, m0, n0, kt + 128, s1, w, lane);
    gemm_step128(s2, wr, wc, ln15, quad, acc);
    kt += 96;
  }
  // peeled tail: tile 30 (slot0, tile 31 still flying), then tile 31 (drain)
  VWAIT(4); __builtin_amdgcn_s_barrier();
  gemm_step128(s0, wr, wc, ln15, quad, acc);
  VWAIT(0); __builtin_amdgcn_s_barrier();
  gemm_step128(s1, wr, wc, ln15, quad, acc);
}

// ---------------------------------------------------------------------------
// Fused QKV projection: z=0 -> Q (scaled log2e/8) [B,H,N,dk]; z=1 -> K;
// z=2 -> V transposed [B,H,dk,N]. Biases fp32. 16B vectorized stores via
// per-wave LDS repack.
// ---------------------------------------------------------------------------
__global__ __launch_bounds__(256) void qkv_gemm(
    const __bf16* __restrict__ X,
    const __bf16* __restrict__ Wq, const float* __restrict__ bq,
    const __bf16* __restrict__ Wk, const float* __restrict__ bk,
    const __bf16* __restrict__ Wv, const float* __restrict__ bv,
    __bf16* __restrict__ ws)
{
  __shared__ __align__(16) __bf16 lds[24576];   // 48 KB: 3 K-slots

  const int z = blockIdx.z;
  const __bf16* W    = (z == 0) ? Wq : (z == 1) ? Wk : Wv;
  const float*  bias = (z == 0) ? bq : (z == 1) ? bk : bv;
  __bf16* out = ws + ((z == 0) ? QOFF : (z == 1) ? KOFF : VOFF);
  // softmax runs in exp2 domain: fold 1/sqrt(dk) * log2(e) into Q
  const float scale = (z == 0) ? 0.125f * 1.44269504088896f : 1.0f;

  const int m0 = blockIdx.x * 128;
  const int n0 = blockIdx.y * 128;

  f32x4 acc[4][4];
  gemm128_core(X, W, m0, n0, lds, acc);

  const int t = threadIdx.x, w = t >> 6, lane = t & 63;
  const int ln15 = lane & 15, quad = lane >> 4;
  const int wr = (w >> 1) << 6, wc = (w & 1) << 6;

  // bias values for this wave's 64 columns (col = j*16+ln15)
  float bj4[4];
#pragma unroll
  for (int j = 0; j < 4; ++j) bj4[j] = bias[n0 + wc + j * 16 + ln15];

  __syncthreads();                     // all waves done reading K-tiles
  __bf16* scr = lds + (w << 10);       // per-wave 1024-elem scratch (2 KB)

  const int bb = m0 >> 11;             // batch (blocks never straddle)
  const int s_base = (m0 & 2047) + wr;
  const int h = (n0 + wc) >> 6;

  if (z != 2) {
    // ---- Q/K [B,H,N,dk]: row-major scratch [row16][d64], coalesced stores
    const int rdrow = lane & 15, rdseg = lane >> 4;
#pragma unroll
    for (int i = 0; i < 4; ++i) {
#pragma unroll
      for (int j = 0; j < 4; ++j)
#pragma unroll
        for (int rr = 0; rr < 4; ++rr)
          scr[(quad * 4 + rr) * 64 + j * 16 + ln15] =
              (__bf16)((acc[i][j][rr] + bj4[j]) * scale);
      // wave-private scratch: compiler orders via lgkmcnt, no barrier
      bf16x8 v0 = *(const bf16x8*)&scr[rdrow * 64 + rdseg * 16];
      bf16x8 v1 = *(const bf16x8*)&scr[rdrow * 64 + rdseg * 16 + 8];
      const int s = s_base + i * 16 + rdrow;
      __bf16* p = out + (((size_t)(bb * NHEAD + h)) * SEQ + s) * DKH + rdseg * 16;
      *(bf16x8*)p = v0;
      *(bf16x8*)&p[8] = v1;
    }
  } else {
    // ---- V^T [B,H,dk,N]: col-major scratch [d64][row16] does the transpose;
    // each lane then stores 32B contiguous in s.
#pragma unroll
    for (int i = 0; i < 4; ++i) {
#pragma unroll
      for (int j = 0; j < 4; ++j) {
        bf16x4 pk;
#pragma unroll
        for (int rr = 0; rr < 4; ++rr) pk[rr] = (__bf16)(acc[i][j][rr] + bj4[j]);
        *(bf16x4*)&scr[(j * 16 + ln15) * 16 + quad * 4] = pk;
      }
      bf16x8 c0 = *(const bf16x8*)&scr[lane * 16];
      bf16x8 c1 = *(const bf16x8*)&scr[lane * 16 + 8];
      __bf16* p = out + (((size_t)(bb * NHEAD + h)) * DKH + lane) * SEQ
                      + s_base + i * 16;
      *(bf16x8*)p = c0;
      *(bf16x8*)&p[8] = c1;
    }
  }
}

// ---------------------------------------------------------------------------
// Output projection: d_out(fp32) = O[M,K]bf16 @ Wo[N,K]bf16^T + bo(fp32).
// 64x128 tile -> 512 blocks (2/CU). Same T4 triple-buffer K-loop (3 loads/
// thread/step -> vmcnt(3) steady-state). LDS: 3 x 6144 = 36 KB.
// ---------------------------------------------------------------------------
__device__ __forceinline__ void out_stage(
    const __bf16* __restrict__ A, const __bf16* __restrict__ Wo,
    int m0, int n0, int kt, __bf16* slot, int w, int lane)
{
  {  // A: 64 rows x 4 chunks = 256 chunks = 1 issue
    const int c = (w << 6) + lane;
    const int row = c >> 2;
    const int goff = ((c & 3) ^ (row & 3)) << 3;
    async16(A + (size_t)(m0 + row) * KDIM + kt + goff, slot + c * 8);
  }
#pragma unroll
  for (int issue = 0; issue < 2; ++issue) {  // B: 128 rows x 4 chunks = 2 issues
    const int cbase = issue * 256 + (w << 6);
    const int c = cbase + lane;
    const int row = c >> 2;
    const int goff = ((c & 3) ^ (row & 3)) << 3;
    async16(Wo + (size_t)(n0 + row) * KDIM + kt + goff, slot + 2048 + cbase * 8);
  }
}

__device__ __forceinline__ void out_step(
    const __bf16* slot, int w, int ln15, int quad, f32x4 (&acc)[4][2])
{
  const __bf16* A_lds = slot;
  const __bf16* B_lds = slot + 2048;
  bf16x8 af[4], bfr[2];
#pragma unroll
  for (int i = 0; i < 4; ++i) {
    const int row = i * 16 + ln15;
    af[i] = *(const bf16x8*)&A_lds[row * 32 + ((quad ^ (row & 3)) << 3)];
  }
#pragma unroll
  for (int j = 0; j < 2; ++j) {
    const int row = (w << 5) + j * 16 + ln15;
    bfr[j] = *(const bf16x8*)&B_lds[row * 32 + ((quad ^ (row & 3)) << 3)];
  }
#pragma unroll
  for (int i = 0; i < 4; ++i)
#pragma unroll
    for (int j = 0; j < 2; ++j)
      acc[i][j] = __builtin_amdgcn_mfma_f32_16x16x32_bf16(af[i], bfr[j], acc[i][j], 0, 0, 0);
}

__global__ __launch_bounds__(256) void out_gemm(
    const __bf16* __restrict__ A, const __bf16* __restrict__ Wo,
    const float* __restrict__ bo, float* __restrict__ out)
{
  __shared__ __align__(16) __bf16 lds[18432];   // 36 KB: 3 slots x 6144

  const int m0 = blockIdx.x * 64;
  const int n0 = blockIdx.y * 128;

  const int t = threadIdx.x, w = t >> 6, lane = t & 63;
  const int ln15 = lane & 15, quad = lane >> 4;

  f32x4 acc[4][2];
#pragma unroll
  for (int i = 0; i < 4; ++i)
#pragma unroll
    for (int j = 0; j < 2; ++j) acc[i][j] = (f32x4){0.f, 0.f, 0.f, 0.f};

  __bf16* s0 = lds;
  __bf16* s1 = lds + 6144;
  __bf16* s2 = lds + 12288;

  out_stage(A, Wo, m0, n0, 0,  s0, w, lane);
  out_stage(A, Wo, m0, n0, 32, s1, w, lane);

  int kt = 0;
#pragma unroll 1
  for (int i3 = 0; i3 < 10; ++i3) {
    VWAIT(3); __builtin_amdgcn_s_barrier();
    out_stage(A, Wo, m0, n0, kt + 64, s2, w, lane);
    out_step(s0, w, ln15, quad, acc);

    VWAIT(3); __builtin_amdgcn_s_barrier();
    out_stage(A, Wo, m0, n0, kt + 96, s0, w, lane);
    out_step(s1, w, ln15, quad, acc);

    VWAIT(3); __builtin_amdgcn_s_barrier();
    out_stage(A, Wo, m0, n0, kt + 128, s1, w, lane);
    out_step(s2, w, ln15, quad, acc);
    kt += 96;
  }
  VWAIT(3); __builtin_amdgcn_s_barrier();
  out_step(s0, w, ln15, quad, acc);
  VWAIT(0); __builtin_amdgcn_s_barrier();
  out_step(s1, w, ln15, quad, acc);

  float bj2[2];
#pragma unroll
  for (int j = 0; j < 2; ++j) bj2[j] = bo[n0 + (w << 5) + j * 16 + ln15];

  __syncthreads();                          // waves done reading tiles
  float* scrf = (float*)lds + (w << 9);     // per-wave 512-float scratch (2 KB)

  const int rdrow = lane & 15, rdseg = lane >> 4;
#pragma unroll
  for (int i = 0; i < 4; ++i) {
#pragma unroll
    for (int j = 0; j < 2; ++j) {
      f32x4 v;
#pragma unroll
      for (int rr = 0; rr < 4; ++rr) v[rr] = acc[i][j][rr] + bj2[j];
      *(f32x4*)&scrf[(j * 16 + ln15) * 16 + quad * 4] = v;   // col-major
    }
    const int m = m0 + i * 16 + rdrow;
    float* p = out + (size_t)m * DMODEL + n0 + (w << 5) + rdseg * 8;
#pragma unroll
    for (int cc = 0; cc < 2; ++cc) {
      f32x4 v;
#pragma unroll
      for (int e = 0; e < 4; ++e)
        v[e] = scrf[(rdseg * 8 + cc * 4 + e) * 16 + rdrow];
      *(f32x4*)&p[cc * 4] = v;
    }
  }
}

// ---------------------------------------------------------------------------
// softmax fragment build (T12): s holds S^T regs for one 32-key block
// (key = (r&3) + 8*(r>>2) + 4*hl, q = ln31). exp2 in place, then
// cvt_pk pairs + permlane32_swap reassemble the PV A-fragments entirely
// in registers — no P LDS round-trip.
// ---------------------------------------------------------------------------
__device__ __forceinline__ void softmax_frag(const f32x16& s, float& l,
                                             bf16x8& pfa, bf16x8& pfb)
{
  float p[16];
#pragma unroll
  for (int r = 0; r < 16; ++r) {
    p[r] = __builtin_amdgcn_exp2f(s[r]);
    l += p[r];
  }
  unsigned A0 = cvtpk_bf16(p[0],  p[1]);   // (0,1)   | (4,5)
  unsigned A1 = cvtpk_bf16(p[2],  p[3]);   // (2,3)   | (6,7)
  unsigned B0 = cvtpk_bf16(p[4],  p[5]);   // (8,9)   | (12,13)
  unsigned B1 = cvtpk_bf16(p[6],  p[7]);   // (10,11) | (14,15)
  unsigned C0 = cvtpk_bf16(p[8],  p[9]);   // (16,17) | (20,21)
  unsigned C1 = cvtpk_bf16(p[10], p[11]);  // (18,19) | (22,23)
  unsigned D0 = cvtpk_bf16(p[12], p[13]);  // (24,25) | (28,29)
  unsigned D1 = cvtpk_bf16(p[14], p[15]);  // (26,27) | (30,31)
  plswap(A0, B0);
  plswap(A1, B1);
  plswap(C0, D0);
  plswap(C1, D1);
  union { unsigned u[4]; bf16x8 v; } ua, ub;
  ua.u[0] = A0; ua.u[1] = A1; ua.u[2] = B0; ua.u[3] = B1;  // k 0..7 | 8..15
  ub.u[0] = C0; ub.u[1] = C1; ub.u[2] = D0; ub.u[3] = D1;  // k 16..23 | 24..31
  pfa = ua.v;
  pfb = ub.v;
}

// ---------------------------------------------------------------------------
// PV step: A-frag PF covers keys kh*64 + KS*16 + hl*8 .. +8
// ---------------------------------------------------------------------------
__device__ __forceinline__ void pvstep(const __bf16* Vs, int kh, int KS, int hl,
                                       int ln31, const bf16x8& PF,
                                       f32x16& o0, f32x16& o1)
{
  const int vchunk = (kh << 3) + 2 * KS + hl;
  bf16x8 vf0 = *(const bf16x8*)&Vs[ln31 * 128 + ((vchunk ^ (ln31 & 15)) << 3)];
  bf16x8 vf1 = *(const bf16x8*)&Vs[(32 + ln31) * 128 +
                                   ((vchunk ^ ((32 + ln31) & 15)) << 3)];
  o0 = __builtin_amdgcn_mfma_f32_32x32x16_bf16(PF, vf0, o0, 0, 0, 0);
  o1 = __builtin_amdgcn_mfma_f32_32x32x16_bf16(PF, vf1, o1, 0, 0, 0);
}

// per-128-key-tile compute for one wave (its 64-key half, two 32-key blocks)
// — R1-verified serial order.
__device__ __forceinline__ void attn_tile_compute(
    const __bf16* Ks, const __bf16* Vs, const bf16x8 (&qf)[4],
    int kh, int ln31, int hl, float& l_lane, f32x16& o0, f32x16& o1)
{
#pragma unroll
  for (int half = 0; half < 2; ++half) {
    f32x16 s;
#pragma unroll
    for (int r = 0; r < 16; ++r) s[r] = 0.f;
    const int kr = (kh << 6) + half * 32 + ln31;
    __builtin_amdgcn_s_setprio(1);
#pragma unroll
    for (int ks = 0; ks < 4; ++ks) {
      bf16x8 kf = *(const bf16x8*)&Ks[kr * 64 + (((2 * ks + hl) ^ (kr & 7)) << 3)];
      s = __builtin_amdgcn_mfma_f32_32x32x16_bf16(kf, qf[ks], s, 0, 0, 0);
    }
    __builtin_amdgcn_s_setprio(0);
    bf16x8 pa, pb;
    softmax_frag(s, l_lane, pa, pb);
    __builtin_amdgcn_s_setprio(1);
    pvstep(Vs, kh, half * 2 + 0, hl, ln31, pa, o0, o1);
    pvstep(Vs, kh, half * 2 + 1, hl, ln31, pb, o0, o1);
    __builtin_amdgcn_s_setprio(0);
  }
}

// ---------------------------------------------------------------------------
// Flash attention — R7 version unchanged (best measured: 43.7 µs). Attn is
// structurally converged (6 attempts: occupancy x2 won; dbuf/reorder/
// drain-amortize/occupancy-x4/T14 all neutral-to-negative). This round
// changes only the GEMMs (T4 counted-vmcnt) — attn is the control.
// ---------------------------------------------------------------------------
__global__ __launch_bounds__(512, 2) void attn_kernel(
    const __bf16* __restrict__ Qb, const __bf16* __restrict__ Kb,
    const __bf16* __restrict__ Vtb, __bf16* __restrict__ Ob)
{
  __shared__ __align__(16) __bf16 smem[3 * 128 * 64];   // 48 KB
  __bf16* QP = smem;            // Q tile [q128][dk64]
  __bf16* Ks = smem + 8192;     // K tile [key128][dk64]
  __bf16* Vs = smem + 16384;    // V tile [d64][key128]

  const int t = threadIdx.x, w = t >> 6, lane = t & 63;
  const int ln31 = lane & 31, hl = lane >> 5;
  const int g  = w & 3;         // q-group (32 rows of the 128-q tile)
  const int kh = w >> 2;        // key-half (64 keys) of the staged tile
  const int bh = blockIdx.x;    // b*NHEAD + h  (XCD-locality key)
  const int q0 = blockIdx.y * 128;
  const int bb = bh >> 4, hh = bh & 15;

  const __bf16* Qg = Qb + (size_t)bh * SEQ * DKH + (size_t)q0 * DKH;
  const __bf16* Kg = Kb + (size_t)bh * SEQ * DKH;
  const __bf16* Vg = Vtb + (size_t)bh * DKH * SEQ;

  // stage Q tile (128x64 = 1024 chunks / 512 threads = 2 issues, gload_lds)
#pragma unroll
  for (int issue = 0; issue < 2; ++issue) {
    const int cbase = issue * 512 + (w << 6);
    const int c = cbase + lane;
    const int row = c >> 3;                         // 8 chunks per 64-elem row
    const int goff = ((c & 7) ^ (row & 7)) << 3;
    async16(Qg + (size_t)row * DKH + goff, QP + cbase * 8);
  }

  // reg-staged K/V (T14 form; neutral vs R1 but not worse — kept)
  const int c0 = t, c1 = t + 512;
  const int krow0 = c0 >> 3; const int kgo0 = ((c0 & 7) ^ (krow0 & 7)) << 3;
  const int krow1 = c1 >> 3; const int kgo1 = ((c1 & 7) ^ (krow1 & 7)) << 3;
  const int vrow0 = c0 >> 4; const int vgo0 = ((c0 & 15) ^ (vrow0 & 15)) << 3;
  const int vrow1 = c1 >> 4; const int vgo1 = ((c1 & 15) ^ (vrow1 & 15)) << 3;
  const __bf16* kp0 = Kg + (size_t)krow0 * DKH + kgo0;   // + kt*DKH per tile
  const __bf16* kp1 = Kg + (size_t)krow1 * DKH + kgo1;
  const __bf16* vp0 = Vg + (size_t)vrow0 * SEQ + vgo0;   // + kt per tile
  const __bf16* vp1 = Vg + (size_t)vrow1 * SEQ + vgo1;
  __bf16* kd0 = Ks + c0 * 8;  __bf16* kd1 = Ks + c1 * 8;
  __bf16* vd0 = Vs + c0 * 8;  __bf16* vd1 = Vs + c1 * 8;

  // issue tile-0 K/V loads into regs (overlaps Q staging + frag setup)
  bf16x8 krg0 = *(const bf16x8*)kp0;
  bf16x8 krg1 = *(const bf16x8*)kp1;
  bf16x8 vrg0 = *(const bf16x8*)vp0;
  bf16x8 vrg1 = *(const bf16x8*)vp1;

  __syncthreads();   // Q tile valid

  // Q B-fragments for this wave's 32 q-rows (held in regs for whole kernel)
  const int qrow = (g << 5) + ln31;
  bf16x8 qf[4];
#pragma unroll
  for (int ks = 0; ks < 4; ++ks) {
    const int chunk = ((2 * ks + hl) ^ (qrow & 7));
    qf[ks] = *(const bf16x8*)&QP[qrow * 64 + (chunk << 3)];
  }

  float l_lane = 0.f;          // partial row-sum for q-row `qrow` (this key-half)
  f32x16 o0, o1;               // partial O[32q][64d]: d-blocks 0/1; d = db*32+ln31
#pragma unroll
  for (int r = 0; r < 16; ++r) { o0[r] = 0.f; o1[r] = 0.f; }

  for (int kt = 0; kt < SEQ; kt += 128) {
    __syncthreads();   // prior tile's Ks/Vs reads done; iter 0: Q reads done
    // write current tile's regs -> LDS (only exposed staging cost)
    *(bf16x8*)kd0 = krg0;  *(bf16x8*)kd1 = krg1;
    *(bf16x8*)vd0 = vrg0;  *(bf16x8*)vd1 = vrg1;
    __syncthreads();   // Ks/Vs valid
    if (kt + 128 < SEQ) {
      // issue next tile's loads; latency hides under this tile's compute
      krg0 = *(const bf16x8*)(kp0 + (size_t)(kt + 128) * DKH);
      krg1 = *(const bf16x8*)(kp1 + (size_t)(kt + 128) * DKH);
      vrg0 = *(const bf16x8*)(vp0 + kt + 128);
      vrg1 = *(const bf16x8*)(vp1 + kt + 128);
    }
    attn_tile_compute(Ks, Vs, qf, kh, ln31, hl, l_lane, o0, o1);
  }

  // ---- cross-wave combine: pair (w, w+4) holds same q-rows, disjoint keys.
  // Waves 4..7 dump partial O (8 KB each) + l into dead Q/K LDS; waves
  // 0..3 sum, normalize, store.
  __syncthreads();                       // all Ks/Vs LDS reads done
  float* cmb = (float*)smem;             // pair region: [d64][q32] f32
  const int dsw = ln31 & 7;
  l_lane += __shfl_xor(l_lane, 32);      // both key-sub-blocks of this wave

  if (w >= 4) {
    float* base = cmb + (g << 11);
#pragma unroll
    for (int gg = 0; gg < 4; ++gg) {
      const int qq = ((2 * gg + hl) ^ dsw) << 2;   // swizzled q-quad slot
      f32x4 va, vb;
#pragma unroll
      for (int rr = 0; rr < 4; ++rr) { va[rr] = o0[4 * gg + rr]; vb[rr] = o1[4 * gg + rr]; }
      *(f32x4*)&base[ln31 * 32 + qq]        = va;   // d = ln31
      *(f32x4*)&base[(32 + ln31) * 32 + qq] = vb;   // d = 32+ln31
    }
    if (hl == 0) cmb[8192 + (g << 5) + ln31] = l_lane;   // l region
  }
  __syncthreads();
  if (w < 4) {
    float* base = cmb + (g << 11);
#pragma unroll
    for (int gg = 0; gg < 4; ++gg) {
      const int qq = ((2 * gg + hl) ^ dsw) << 2;
      const f32x4 va = *(const f32x4*)&base[ln31 * 32 + qq];
      const f32x4 vb = *(const f32x4*)&base[(32 + ln31) * 32 + qq];
#pragma unroll
      for (int rr = 0; rr < 4; ++rr) { o0[4 * gg + rr] += va[rr]; o1[4 * gg + rr] += vb[rr]; }
    }
    const float inv = 1.0f / (l_lane + cmb[8192 + (g << 5) + ln31]);

    // epilogue: O[b, q, h*64+d]; lane = d col; fetch inv via shfl
#pragma unroll
    for (int r = 0; r < 16; ++r) {
      const int qi = (r & 3) + 8 * (r >> 2) + 4 * hl;    // q within wave's 32
      const float iq = __shfl(inv, qi);                  // from lane qi (hl=0 half)
      const int q = q0 + (g << 5) + qi;
      __bf16* rowp = Ob + ((size_t)(bb * SEQ + q)) * DMODEL + hh * DKH;
      rowp[ln31]      = (__bf16)(o0[r] * iq);
      rowp[32 + ln31] = (__bf16)(o1[r] * iq);
    }
  }
}

// ---------------------------------------------------------------------------
extern "C" void kernel_launch(void* const* d_in, const int* in_sizes, int n_in,
                              void* d_out, int out_size, void* d_ws, size_t ws_size,
                              hipStream_t stream)
{
  const float* x  = (const float*)d_in[0];
  const float* Wq = (const float*)d_in[1];
  const float* bq = (const float*)d_in[2];
  const float* Wk = (const float*)d_in[3];
  const float* bk = (const float*)d_in[4];
  const float* Wv = (const float*)d_in[5];
  const float* bv = (const float*)d_in[6];
  const float* Wo = (const float*)d_in[7];
  const float* bo = (const float*)d_in[8];
  float*  out = (float*)d_out;
  __bf16* ws  = (__bf16*)d_ws;

  // fp32 -> bf16 for x and the 4 weight matrices (one launch)
  cvt_fp32_bf16<<<dim3(2048, 5, 1), 256, 0, stream>>>(x, Wq, Wk, Wv, Wo, ws);

  // Q,K,V projections (fused, grid.z picks the matrix)
  qkv_gemm<<<dim3(MTOT / 128, DMODEL / 128, 3), 256, 0, stream>>>(
      ws + XB, ws + WQB, bq, ws + WKB, bk, ws + WVB, bv, ws);

  // flash attention: (bh, q-tile of 128) = 512 blocks x 512 threads
  attn_kernel<<<dim3(BATCH * NHEAD, SEQ / 128), 512, 0, stream>>>(
      ws + QOFF, ws + KOFF, ws + VOFF, ws + OOFF);

  // output projection -> fp32 d_out (64x128 tiles, 512 blocks)
  out_gemm<<<dim3(MTOT / 64, DMODEL / 128), 256, 0, stream>>>(
      ws + OOFF, ws + WOB, bo, out);
}